// Round 3
// baseline (6365.510 us; speedup 1.0000x reference)
//
#include <hip/hip_runtime.h>
#include <hip/hip_bf16.h>

#define B_ 8
#define T_ 2048
#define C_ 400
#define H_ 4
#define D_ 100
#define TM 8

typedef __hip_bfloat16 bf16;

__device__ __forceinline__ float bf2f(bf16 v){ return __bfloat162float(v); }
__device__ __forceinline__ bf16 f2bf(float f){ return __float2bfloat16(f); }
__device__ __forceinline__ unsigned short bfbits(float f){
  bf16 h = f2bf(f);
  return __builtin_bit_cast(unsigned short, h);
}

// ---------------------------------------------------------------------------
// Wo^T fp32 (so out-proj weight reads are coalesced over n)
__global__ void wo_prep_kernel(const float* __restrict__ Wo, float* __restrict__ WoT){
  int i = blockIdx.x * blockDim.x + threadIdx.x;
  if (i < C_*C_){
    int n = i / C_, c = i % C_;
    WoT[c*C_ + n] = Wo[i];
  }
}

// ---------------------------------------------------------------------------
// QKV projection (fp32 in, fp32 accum): per block, TM=8 rows of x staged in
// LDS transposed [c][t]. Outputs: Q fp32 [B,H,T,D] (row-major, wave-uniform
// scalar q loads in attn), K,V bf16 [B,H,D,T] (d-major, coalesced per-key
// lane loads in attn).
__global__ __launch_bounds__(256) void qkv_proj_kernel(const float* __restrict__ x,
    const float* __restrict__ Wq, const float* __restrict__ Wk, const float* __restrict__ Wv,
    float* __restrict__ Qf, bf16* __restrict__ KT, bf16* __restrict__ VT){
  __shared__ __align__(16) float xs[C_ * TM];   // [c][t]
  int bid = blockIdx.x;
  int b = bid / (T_/TM);
  int t0 = (bid % (T_/TM)) * TM;
  int tid = threadIdx.x;
  for (int i = tid; i < TM*C_; i += 256){
    int t = i / C_, c = i % C_;
    xs[c*TM + t] = x[(size_t)(b*T_ + t0 + t)*C_ + c];
  }
  __syncthreads();

  float acc[5][TM];
  #pragma unroll
  for (int s=0;s<5;++s){
    #pragma unroll
    for (int t=0;t<TM;++t) acc[s][t]=0.f;
  }
  // output slot o = p*400 + h*100 + d  (p: 0=q,1=k,2=v), o = s*256+tid
  const float* wptr[5];
  int pp[5], dd[5], hh[5]; bool val[5];
  #pragma unroll
  for (int s=0;s<5;++s){
    int o = s*256 + tid;
    val[s] = (o < 3*H_*D_);
    int oc = val[s] ? o : 0;
    int p = oc / (H_*D_), rem = oc % (H_*D_);
    int h = rem / D_, d = rem % D_;
    const float* W = (p==0) ? Wq : (p==1) ? Wk : Wv;
    wptr[s] = W + h*(C_*D_) + d;
    pp[s]=p; hh[s]=h; dd[s]=d;
  }
  for (int c=0;c<C_;++c){
    float wv[5];
    #pragma unroll
    for (int s=0;s<5;++s) wv[s] = wptr[s][c*D_];
    float4 x0 = *reinterpret_cast<const float4*>(&xs[c*TM]);
    float4 x1 = *reinterpret_cast<const float4*>(&xs[c*TM+4]);
    float xv[8] = {x0.x,x0.y,x0.z,x0.w,x1.x,x1.y,x1.z,x1.w};
    #pragma unroll
    for (int t=0;t<TM;++t){
      #pragma unroll
      for (int s=0;s<5;++s) acc[s][t] = fmaf(xv[t], wv[s], acc[s][t]);
    }
  }
  #pragma unroll
  for (int s=0;s<5;++s){
    if (!val[s]) continue;
    int p=pp[s], h=hh[s], d=dd[s];
    size_t bh = (size_t)b*H_ + h;
    if (p == 0){
      #pragma unroll
      for (int t=0;t<TM;++t)
        Qf[(bh*T_ + t0 + t)*D_ + d] = acc[s][t];
    } else {
      unsigned int u[4];
      #pragma unroll
      for (int t2=0; t2<4; ++t2)
        u[t2] = (unsigned)bfbits(acc[s][2*t2]) | ((unsigned)bfbits(acc[s][2*t2+1]) << 16);
      bf16* base = (p==1 ? KT : VT) + (bh*D_ + d)*T_ + t0;
      *reinterpret_cast<uint4*>(base) = make_uint4(u[0],u[1],u[2],u[3]);   // 16B aligned: t0%8==0
    }
  }
}

// ---------------------------------------------------------------------------
// Flash attention, 1 wave per query row. Lane l owns key s0+l of each 64-key
// chunk; K/V loads are 128B coalesced (d-major layout). acc[100] in VGPRs,
// online softmax with exact running max. Final cross-lane transpose-reduce via
// small LDS (64x17 floats = 4.4 KB: stride 17 odd -> 2 lanes/bank = free).
// bid mapping: XCD (bid&7) owns 4 (b,h) pairs, t contiguous -> L2 locality.
__global__ __launch_bounds__(64) void attn_kernel(const float* __restrict__ Qf,
    const bf16* __restrict__ KT, const bf16* __restrict__ VT, float* __restrict__ AO){
  __shared__ float red[64*17];
  int bid = blockIdx.x;
  int xcd = bid & 7;
  int idx = bid >> 3;
  int bh  = xcd*4 + (idx >> 11);
  int t   = idx & (T_-1);
  int l = threadIdx.x;
  const float* __restrict__ qrow = Qf + ((size_t)bh*T_ + t)*D_;
  const bf16* __restrict__ KTb = KT + (size_t)bh*D_*T_;
  const bf16* __restrict__ VTb = VT + (size_t)bh*D_*T_;
  float acc[D_];
  #pragma unroll
  for (int d=0;d<D_;++d) acc[d] = 0.f;
  float m = -__builtin_inff(), lr = 0.f;
  int nch = (t >> 6) + 1;
  for (int j = 0; j < nch; ++j){
    int s = (j << 6) + l;
    const bf16* kp = KTb + s;
    float sc0=0.f, sc1=0.f, sc2=0.f, sc3=0.f;
    #pragma unroll 5
    for (int d=0; d<D_; d+=4){
      sc0 = fmaf(qrow[d  ], bf2f(kp[(size_t)(d  )*T_]), sc0);
      sc1 = fmaf(qrow[d+1], bf2f(kp[(size_t)(d+1)*T_]), sc1);
      sc2 = fmaf(qrow[d+2], bf2f(kp[(size_t)(d+2)*T_]), sc2);
      sc3 = fmaf(qrow[d+3], bf2f(kp[(size_t)(d+3)*T_]), sc3);
    }
    float sc = ((sc0+sc1)+(sc2+sc3)) * 0.1f;     // 1/sqrt(100)
    if (s > t) sc = -__builtin_inff();
    float cmax = sc;
    #pragma unroll
    for (int mm=32; mm>0; mm>>=1) cmax = fmaxf(cmax, __shfl_xor(cmax, mm));
    float mnew = fmaxf(m, cmax);
    if (mnew > m){                                // wave-uniform branch
      float scale = __expf(m - mnew);
      lr *= scale;
      #pragma unroll
      for (int d=0;d<D_;++d) acc[d] *= scale;
      m = mnew;
    }
    float p = __expf(sc - m);                     // masked lanes: exp(-inf)=0
    float psum = p;
    #pragma unroll
    for (int mm=32; mm>0; mm>>=1) psum += __shfl_xor(psum, mm);
    lr += psum;
    const bf16* vp = VTb + s;
    #pragma unroll
    for (int d=0; d<D_; ++d)
      acc[d] = fmaf(p, bf2f(vp[(size_t)d*T_]), acc[d]);
  }
  float inv = 1.f / lr;
  int b = bh >> 2, h = bh & 3;
  float* ao = AO + ((size_t)(b*T_ + t))*C_ + h*D_;
  int quarter = l >> 4;      // 0..3
  int dloc = l & 15;
  #pragma unroll
  for (int g=0; g<7; ++g){
    #pragma unroll
    for (int k=0; k<16; ++k){
      int di = g*16 + k;
      red[l*17 + k] = (di < D_) ? acc[di] : 0.f;
    }
    __syncthreads();
    float sum = 0.f;
    #pragma unroll
    for (int ss=0; ss<16; ++ss) sum += red[(quarter*16+ss)*17 + dloc];
    sum += __shfl_xor(sum, 16);
    sum += __shfl_xor(sum, 32);
    int d = g*16 + dloc;
    if (d < D_) ao[d] = sum * inv;                // 4x redundant, same value
    __syncthreads();
  }
}

// ---------------------------------------------------------------------------
// out = AO @ Wo^T + bo (all fp32), WoT pre-transposed so weight reads
// coalesce over n.
__global__ __launch_bounds__(256) void out_proj_kernel(const float* __restrict__ AO,
    const float* __restrict__ WoT, const float* __restrict__ bo, float* __restrict__ out){
  __shared__ __align__(16) float as[C_ * TM];    // [c][t]
  int bid = blockIdx.x;
  int b = bid / (T_/TM);
  int t0 = (bid % (T_/TM)) * TM;
  int tid = threadIdx.x;
  for (int i = tid; i < TM*C_; i += 256){
    int t = i / C_, c = i % C_;
    as[c*TM + t] = AO[(size_t)(b*T_ + t0 + t)*C_ + c];
  }
  __syncthreads();
  float acc0[TM], acc1[TM];
  #pragma unroll
  for (int t=0;t<TM;++t){ acc0[t]=0.f; acc1[t]=0.f; }
  int n0 = tid;
  int n1 = tid + 256;
  bool v1 = (n1 < C_);
  int n1c = v1 ? n1 : 0;
  for (int c=0;c<C_;++c){
    float w0 = WoT[c*C_ + n0];
    float w1 = WoT[c*C_ + n1c];
    float4 a0 = *reinterpret_cast<const float4*>(&as[c*TM]);
    float4 a1 = *reinterpret_cast<const float4*>(&as[c*TM+4]);
    float av[8] = {a0.x,a0.y,a0.z,a0.w,a1.x,a1.y,a1.z,a1.w};
    #pragma unroll
    for (int t=0;t<TM;++t){
      acc0[t] = fmaf(av[t], w0, acc0[t]);
      acc1[t] = fmaf(av[t], w1, acc1[t]);
    }
  }
  float b0 = bo[n0];
  float b1 = bo[n1c];
  #pragma unroll
  for (int t=0;t<TM;++t){
    size_t row = (size_t)(b*T_ + t0 + t)*C_;
    out[row + n0] = acc0[t] + b0;
    if (v1) out[row + n1] = acc1[t] + b1;
  }
}

// ---------------------------------------------------------------------------
extern "C" void kernel_launch(void* const* d_in, const int* in_sizes, int n_in,
                              void* d_out, int out_size, void* d_ws, size_t ws_size,
                              hipStream_t stream){
  const float* x  = (const float*)d_in[0];
  const float* Wq = (const float*)d_in[1];
  const float* Wk = (const float*)d_in[2];
  const float* Wv = (const float*)d_in[3];
  const float* Wo = (const float*)d_in[4];
  const float* bo = (const float*)d_in[5];

  constexpr size_t NXB = (size_t)B_*T_*C_;   // 6,553,600 (= B*H*T*D)
  constexpr size_t OFF_QF  = 0;
  constexpr size_t OFF_KT  = OFF_QF + NXB*4;
  constexpr size_t OFF_VT  = OFF_KT + NXB*2;
  constexpr size_t OFF_AO  = OFF_VT + NXB*2;
  constexpr size_t OFF_WOT = OFF_AO + NXB*4;
  constexpr size_t TOTAL   = OFF_WOT + (size_t)C_*C_*4;   // ~79.3 MB
  if (ws_size < TOTAL) return;   // visible failure signature (output stays zero)

  char* ws = (char*)d_ws;
  float* Qf   = (float*)(ws + OFF_QF);
  bf16*  KTp  = (bf16*)(ws + OFF_KT);
  bf16*  VTp  = (bf16*)(ws + OFF_VT);
  float* AO   = (float*)(ws + OFF_AO);
  float* WoT  = (float*)(ws + OFF_WOT);
  float* out  = (float*)d_out;

  wo_prep_kernel<<<625, 256, 0, stream>>>(Wo, WoT);
  qkv_proj_kernel<<<B_*(T_/TM), 256, 0, stream>>>(x, Wq, Wk, Wv, Qf, KTp, VTp);
  attn_kernel<<<B_*H_*T_, 64, 0, stream>>>(Qf, KTp, VTp, AO);
  out_proj_kernel<<<B_*(T_/TM), 256, 0, stream>>>(AO, WoT, bo, out);
}

// Round 4
// 1355.304 us; speedup vs baseline: 4.6967x; 4.6967x over previous
//
#include <hip/hip_runtime.h>
#include <hip/hip_bf16.h>

#define B_ 8
#define T_ 2048
#define C_ 400
#define H_ 4
#define D_ 100
#define TM 8

typedef __hip_bfloat16 bf16;
typedef unsigned int uint32;
typedef unsigned short ushort16;

__device__ __forceinline__ float bf2f(bf16 v){ return __bfloat162float(v); }
__device__ __forceinline__ bf16 f2bf(float f){ return __float2bfloat16(f); }
__device__ __forceinline__ unsigned short bfbits(float f){
  bf16 h = f2bf(f);
  return __builtin_bit_cast(unsigned short, h);
}
// bf16x2 (packed in uint) -> two f32: lo = u<<16, hi = u&0xffff0000
__device__ __forceinline__ float lo16(uint32 u){ return __builtin_bit_cast(float, u << 16); }
__device__ __forceinline__ float hi16(uint32 u){ return __builtin_bit_cast(float, u & 0xffff0000u); }

// ---------------------------------------------------------------------------
// Wo^T fp32 (so out-proj weight reads are coalesced over n)
__global__ void wo_prep_kernel(const float* __restrict__ Wo, float* __restrict__ WoT){
  int i = blockIdx.x * blockDim.x + threadIdx.x;
  if (i < C_*C_){
    int n = i / C_, c = i % C_;
    WoT[c*C_ + n] = Wo[i];
  }
}

// ---------------------------------------------------------------------------
// QKV projection (fp32 in, fp32 accum): per block, TM=8 rows of x staged in
// LDS transposed [c][t]. Outputs: Q fp32 [B,H,T,D] row-major (uniform scalar
// loads in attn), K bf16 [B,H,D,T] d-major (lane-owns-key score loads),
// V bf16 [B,H,T,D] t-major (lane-owns-d PV loads).
__global__ __launch_bounds__(256) void qkv_proj_kernel(const float* __restrict__ x,
    const float* __restrict__ Wq, const float* __restrict__ Wk, const float* __restrict__ Wv,
    float* __restrict__ Qf, bf16* __restrict__ KT, bf16* __restrict__ Vt){
  __shared__ __align__(16) float xs[C_ * TM];   // [c][t]
  int bid = blockIdx.x;
  int b = bid / (T_/TM);
  int t0 = (bid % (T_/TM)) * TM;
  int tid = threadIdx.x;
  for (int i = tid; i < TM*C_; i += 256){
    int t = i / C_, c = i % C_;
    xs[c*TM + t] = x[(size_t)(b*T_ + t0 + t)*C_ + c];
  }
  __syncthreads();

  float acc[5][TM];
  #pragma unroll
  for (int s=0;s<5;++s){
    #pragma unroll
    for (int t=0;t<TM;++t) acc[s][t]=0.f;
  }
  // output slot o = p*400 + h*100 + d  (p: 0=q,1=k,2=v), o = s*256+tid
  const float* wptr[5];
  int pp[5], dd[5], hh[5]; bool val[5];
  #pragma unroll
  for (int s=0;s<5;++s){
    int o = s*256 + tid;
    val[s] = (o < 3*H_*D_);
    int oc = val[s] ? o : 0;
    int p = oc / (H_*D_), rem = oc % (H_*D_);
    int h = rem / D_, d = rem % D_;
    const float* W = (p==0) ? Wq : (p==1) ? Wk : Wv;
    wptr[s] = W + h*(C_*D_) + d;
    pp[s]=p; hh[s]=h; dd[s]=d;
  }
  for (int c=0;c<C_;++c){
    float wv[5];
    #pragma unroll
    for (int s=0;s<5;++s) wv[s] = wptr[s][c*D_];
    float4 x0 = *reinterpret_cast<const float4*>(&xs[c*TM]);
    float4 x1 = *reinterpret_cast<const float4*>(&xs[c*TM+4]);
    float xv[8] = {x0.x,x0.y,x0.z,x0.w,x1.x,x1.y,x1.z,x1.w};
    #pragma unroll
    for (int t=0;t<TM;++t){
      #pragma unroll
      for (int s=0;s<5;++s) acc[s][t] = fmaf(xv[t], wv[s], acc[s][t]);
    }
  }
  #pragma unroll
  for (int s=0;s<5;++s){
    if (!val[s]) continue;
    int p=pp[s], h=hh[s], d=dd[s];
    size_t bh = (size_t)b*H_ + h;
    if (p == 0){
      #pragma unroll
      for (int t=0;t<TM;++t)
        Qf[(bh*T_ + t0 + t)*D_ + d] = acc[s][t];
    } else if (p == 1){
      unsigned int u[4];
      #pragma unroll
      for (int t2=0; t2<4; ++t2)
        u[t2] = (unsigned)bfbits(acc[s][2*t2]) | ((unsigned)bfbits(acc[s][2*t2+1]) << 16);
      bf16* base = KT + (bh*D_ + d)*T_ + t0;
      *reinterpret_cast<uint4*>(base) = make_uint4(u[0],u[1],u[2],u[3]);   // 16B aligned: t0%8==0
    } else {
      #pragma unroll
      for (int t=0;t<TM;++t)
        Vt[(bh*T_ + t0 + t)*D_ + d] = f2bf(acc[s][t]);
    }
  }
}

// ---------------------------------------------------------------------------
// Flash attention, 1 wave per query row, 128-key chunks.
// Phase 1 (score): lane l owns keys s0+2l, s0+2l+1; K is d-major so each
//   uint load fetches both keys' bf16 for one d, coalesced across the wave.
//   Q is read wave-uniform (scalar cache).
// Phase 2 (PV): p[128] shared via 512B LDS (float4 broadcast reads); lane l
//   owns d=2l,2l+1; V is t-major so each ushort2 load is coalesced.
// Per-thread state ~30 VGPRs -> no spill (the R3 6ms pathology).
// bid mapping: XCD (bid&7) owns 4 (b,h) pairs, t contiguous -> L2 locality.
__global__ __launch_bounds__(64) void attn_kernel(const float* __restrict__ Qf,
    const bf16* __restrict__ KT, const bf16* __restrict__ Vt, float* __restrict__ AO){
  __shared__ __align__(16) float plds[128];
  int bid = blockIdx.x;
  int xcd = bid & 7;
  int idx = bid >> 3;
  int bh  = xcd*4 + (idx >> 11);
  int t   = idx & (T_-1);
  int l = threadIdx.x;
  const float* __restrict__ qrow = Qf + ((size_t)bh*T_ + t)*D_;
  const ushort16* __restrict__ Kb = (const ushort16*)(KT + (size_t)bh*D_*T_);
  const ushort16* __restrict__ Vb = (const ushort16*)(Vt + (size_t)bh*T_*D_);
  int d0 = 2*l;
  int d0c = (d0 > D_-2) ? (D_-2) : d0;     // clamp V-load addr for lanes 50..63
  float acc0 = 0.f, acc1 = 0.f;
  float m = -__builtin_inff(), lr = 0.f;
  int nch = (t >> 7) + 1;
  for (int j = 0; j < nch; ++j){
    int s0 = j << 7;
    int sA = s0 + 2*l;
    // ---- scores for keys sA, sA+1 ----
    const ushort16* kp = Kb + sA;           // + d*T_ per dim
    float xa0=0.f, ya0=0.f, xa1=0.f, ya1=0.f;
    #pragma unroll 5
    for (int d=0; d<D_; d+=4){
      float4 qq = *reinterpret_cast<const float4*>(qrow + d);   // wave-uniform
      uint32 k0 = *reinterpret_cast<const uint32*>(kp + (size_t)(d  )*T_);
      uint32 k1 = *reinterpret_cast<const uint32*>(kp + (size_t)(d+1)*T_);
      uint32 k2 = *reinterpret_cast<const uint32*>(kp + (size_t)(d+2)*T_);
      uint32 k3 = *reinterpret_cast<const uint32*>(kp + (size_t)(d+3)*T_);
      xa0 = fmaf(qq.x, lo16(k0), xa0);  ya0 = fmaf(qq.x, hi16(k0), ya0);
      xa1 = fmaf(qq.y, lo16(k1), xa1);  ya1 = fmaf(qq.y, hi16(k1), ya1);
      xa0 = fmaf(qq.z, lo16(k2), xa0);  ya0 = fmaf(qq.z, hi16(k2), ya0);
      xa1 = fmaf(qq.w, lo16(k3), xa1);  ya1 = fmaf(qq.w, hi16(k3), ya1);
    }
    float scA = (xa0 + xa1) * 0.1f;          // 1/sqrt(100)
    float scB = (ya0 + ya1) * 0.1f;
    if (sA     > t) scA = -__builtin_inff();
    if (sA + 1 > t) scB = -__builtin_inff();
    // ---- online softmax update ----
    float cmax = fmaxf(scA, scB);
    #pragma unroll
    for (int mm=32; mm>0; mm>>=1) cmax = fmaxf(cmax, __shfl_xor(cmax, mm));
    float mnew = fmaxf(m, cmax);             // finite: key s0 <= t always present
    float scale = __expf(m - mnew);          // first chunk: exp(-inf)=0
    acc0 *= scale; acc1 *= scale; lr *= scale;
    m = mnew;
    float pA = __expf(scA - m);              // masked: exp(-inf)=0
    float pB = __expf(scB - m);
    float psum = pA + pB;
    #pragma unroll
    for (int mm=32; mm>0; mm>>=1) psum += __shfl_xor(psum, mm);
    lr += psum;
    // ---- share p across lanes ----
    *reinterpret_cast<float2*>(&plds[2*l]) = make_float2(pA, pB);
    __syncthreads();
    // ---- PV: lane owns d = 2l, 2l+1 ----
    const ushort16* vrow = Vb + (size_t)s0*D_ + d0c;
    #pragma unroll 8
    for (int si=0; si<128; si+=4){
      float4 ppv = *reinterpret_cast<const float4*>(&plds[si]);  // LDS broadcast
      uint32 v0 = *reinterpret_cast<const uint32*>(vrow + (size_t)(si  )*D_);
      uint32 v1 = *reinterpret_cast<const uint32*>(vrow + (size_t)(si+1)*D_);
      uint32 v2 = *reinterpret_cast<const uint32*>(vrow + (size_t)(si+2)*D_);
      uint32 v3 = *reinterpret_cast<const uint32*>(vrow + (size_t)(si+3)*D_);
      acc0 = fmaf(ppv.x, lo16(v0), acc0);  acc1 = fmaf(ppv.x, hi16(v0), acc1);
      acc0 = fmaf(ppv.y, lo16(v1), acc0);  acc1 = fmaf(ppv.y, hi16(v1), acc1);
      acc0 = fmaf(ppv.z, lo16(v2), acc0);  acc1 = fmaf(ppv.z, hi16(v2), acc1);
      acc0 = fmaf(ppv.w, lo16(v3), acc0);  acc1 = fmaf(ppv.w, hi16(v3), acc1);
    }
    __syncthreads();                          // WAR: plds rewritten next chunk
  }
  float inv = 1.f / lr;
  int b = bh >> 2, h = bh & 3;
  if (d0 < D_){
    float* ao = AO + ((size_t)(b*T_ + t))*C_ + h*D_ + d0;
    *reinterpret_cast<float2*>(ao) = make_float2(acc0 * inv, acc1 * inv);
  }
}

// ---------------------------------------------------------------------------
// out = AO @ Wo^T + bo (all fp32), WoT pre-transposed so weight reads
// coalesce over n.
__global__ __launch_bounds__(256) void out_proj_kernel(const float* __restrict__ AO,
    const float* __restrict__ WoT, const float* __restrict__ bo, float* __restrict__ out){
  __shared__ __align__(16) float as[C_ * TM];    // [c][t]
  int bid = blockIdx.x;
  int b = bid / (T_/TM);
  int t0 = (bid % (T_/TM)) * TM;
  int tid = threadIdx.x;
  for (int i = tid; i < TM*C_; i += 256){
    int t = i / C_, c = i % C_;
    as[c*TM + t] = AO[(size_t)(b*T_ + t0 + t)*C_ + c];
  }
  __syncthreads();
  float acc0[TM], acc1[TM];
  #pragma unroll
  for (int t=0;t<TM;++t){ acc0[t]=0.f; acc1[t]=0.f; }
  int n0 = tid;
  int n1 = tid + 256;
  bool v1 = (n1 < C_);
  int n1c = v1 ? n1 : 0;
  for (int c=0;c<C_;++c){
    float w0 = WoT[c*C_ + n0];
    float w1 = WoT[c*C_ + n1c];
    float4 a0 = *reinterpret_cast<const float4*>(&as[c*TM]);
    float4 a1 = *reinterpret_cast<const float4*>(&as[c*TM+4]);
    float av[8] = {a0.x,a0.y,a0.z,a0.w,a1.x,a1.y,a1.z,a1.w};
    #pragma unroll
    for (int t=0;t<TM;++t){
      acc0[t] = fmaf(av[t], w0, acc0[t]);
      acc1[t] = fmaf(av[t], w1, acc1[t]);
    }
  }
  float b0 = bo[n0];
  float b1 = bo[n1c];
  #pragma unroll
  for (int t=0;t<TM;++t){
    size_t row = (size_t)(b*T_ + t0 + t)*C_;
    out[row + n0] = acc0[t] + b0;
    if (v1) out[row + n1] = acc1[t] + b1;
  }
}

// ---------------------------------------------------------------------------
extern "C" void kernel_launch(void* const* d_in, const int* in_sizes, int n_in,
                              void* d_out, int out_size, void* d_ws, size_t ws_size,
                              hipStream_t stream){
  const float* x  = (const float*)d_in[0];
  const float* Wq = (const float*)d_in[1];
  const float* Wk = (const float*)d_in[2];
  const float* Wv = (const float*)d_in[3];
  const float* Wo = (const float*)d_in[4];
  const float* bo = (const float*)d_in[5];

  constexpr size_t NXB = (size_t)B_*T_*C_;   // 6,553,600 (= B*H*T*D)
  constexpr size_t OFF_QF  = 0;
  constexpr size_t OFF_KT  = OFF_QF + NXB*4;
  constexpr size_t OFF_VT  = OFF_KT + NXB*2;
  constexpr size_t OFF_AO  = OFF_VT + NXB*2;
  constexpr size_t OFF_WOT = OFF_AO + NXB*4;
  constexpr size_t TOTAL   = OFF_WOT + (size_t)C_*C_*4;   // ~79.3 MB
  if (ws_size < TOTAL) return;   // visible failure signature (output stays zero)

  char* ws = (char*)d_ws;
  float* Qf   = (float*)(ws + OFF_QF);
  bf16*  KTp  = (bf16*)(ws + OFF_KT);
  bf16*  Vtp  = (bf16*)(ws + OFF_VT);
  float* AO   = (float*)(ws + OFF_AO);
  float* WoT  = (float*)(ws + OFF_WOT);
  float* out  = (float*)d_out;

  wo_prep_kernel<<<625, 256, 0, stream>>>(Wo, WoT);
  qkv_proj_kernel<<<B_*(T_/TM), 256, 0, stream>>>(x, Wq, Wk, Wv, Qf, KTp, Vtp);
  attn_kernel<<<B_*H_*T_, 64, 0, stream>>>(Qf, KTp, Vtp, AO);
  out_proj_kernel<<<B_*(T_/TM), 256, 0, stream>>>(AO, WoT, bo, out);
}

// Round 5
// 677.736 us; speedup vs baseline: 9.3923x; 1.9998x over previous
//
#include <hip/hip_runtime.h>
#include <hip/hip_bf16.h>

#define B_ 8
#define T_ 2048
#define C_ 400
#define H_ 4
#define D_ 100
#define DP 128
#define TM 8

typedef __hip_bfloat16 bf16;
typedef unsigned int uint32;
typedef __attribute__((ext_vector_type(8))) short short8;
typedef __attribute__((ext_vector_type(4))) float f32x4;

__device__ __forceinline__ float bf2f(bf16 v){ return __bfloat162float(v); }
__device__ __forceinline__ bf16 f2bf(float f){ return __float2bfloat16(f); }
__device__ __forceinline__ unsigned short bfbits(float f){
  bf16 h = f2bf(f);
  return __builtin_bit_cast(unsigned short, h);
}
__device__ __forceinline__ uint32 pk2(float a, float b){
  return (uint32)bfbits(a) | ((uint32)bfbits(b) << 16);
}

// ---------------------------------------------------------------------------
// Wo^T fp32 (so out-proj weight reads are coalesced over n)
__global__ void wo_prep_kernel(const float* __restrict__ Wo, float* __restrict__ WoT){
  int i = blockIdx.x * blockDim.x + threadIdx.x;
  if (i < C_*C_){
    int n = i / C_, c = i % C_;
    WoT[c*C_ + n] = Wo[i];
  }
}

// ---------------------------------------------------------------------------
// QKV projection (fp32 in, fp32 accum). Outputs (all bf16, D padded to 128):
//   Qp, Kp: [bh][T][DP] t-major  (MFMA A/B fragment rows; Qp pad pre-zeroed)
//   VT:     [bh][DP][T] d-major  (MFMA B fragment for PV)
__global__ __launch_bounds__(256) void qkv_proj_kernel(const float* __restrict__ x,
    const float* __restrict__ Wq, const float* __restrict__ Wk, const float* __restrict__ Wv,
    bf16* __restrict__ Qp, bf16* __restrict__ Kp, bf16* __restrict__ VT){
  __shared__ __align__(16) float xs[C_ * TM];   // [c][t]
  int bid = blockIdx.x;
  int b = bid / (T_/TM);
  int t0 = (bid % (T_/TM)) * TM;
  int tid = threadIdx.x;
  for (int i = tid; i < TM*C_; i += 256){
    int t = i / C_, c = i % C_;
    xs[c*TM + t] = x[(size_t)(b*T_ + t0 + t)*C_ + c];
  }
  __syncthreads();

  float acc[5][TM];
  #pragma unroll
  for (int s=0;s<5;++s){
    #pragma unroll
    for (int t=0;t<TM;++t) acc[s][t]=0.f;
  }
  // output slot o = p*400 + h*100 + d  (p: 0=q,1=k,2=v), o = s*256+tid
  const float* wptr[5];
  int pp[5], dd[5], hh[5]; bool val[5];
  #pragma unroll
  for (int s=0;s<5;++s){
    int o = s*256 + tid;
    val[s] = (o < 3*H_*D_);
    int oc = val[s] ? o : 0;
    int p = oc / (H_*D_), rem = oc % (H_*D_);
    int h = rem / D_, d = rem % D_;
    const float* W = (p==0) ? Wq : (p==1) ? Wk : Wv;
    wptr[s] = W + h*(C_*D_) + d;
    pp[s]=p; hh[s]=h; dd[s]=d;
  }
  for (int c=0;c<C_;++c){
    float wv[5];
    #pragma unroll
    for (int s=0;s<5;++s) wv[s] = wptr[s][c*D_];
    float4 x0 = *reinterpret_cast<const float4*>(&xs[c*TM]);
    float4 x1 = *reinterpret_cast<const float4*>(&xs[c*TM+4]);
    float xv[8] = {x0.x,x0.y,x0.z,x0.w,x1.x,x1.y,x1.z,x1.w};
    #pragma unroll
    for (int t=0;t<TM;++t){
      #pragma unroll
      for (int s=0;s<5;++s) acc[s][t] = fmaf(xv[t], wv[s], acc[s][t]);
    }
  }
  #pragma unroll
  for (int s=0;s<5;++s){
    if (!val[s]) continue;
    int p=pp[s], h=hh[s], d=dd[s];
    size_t bh = (size_t)b*H_ + h;
    if (p == 2){
      unsigned int u[4];
      #pragma unroll
      for (int t2=0; t2<4; ++t2)
        u[t2] = pk2(acc[s][2*t2], acc[s][2*t2+1]);
      bf16* base = VT + (bh*DP + d)*T_ + t0;
      *reinterpret_cast<uint4*>(base) = make_uint4(u[0],u[1],u[2],u[3]);  // 16B aligned
    } else {
      bf16* dst = (p==0 ? Qp : Kp) + (bh*T_ + t0)*DP + d;
      #pragma unroll
      for (int t=0;t<TM;++t)
        dst[(size_t)t*DP] = f2bf(acc[s][t]);
    }
  }
}

// ---------------------------------------------------------------------------
// MFMA flash attention. Block = 4 independent waves; wave owns 16 q-rows.
// Per 32-key chunk: S^T = mfma(K,Q) (2 k-tiles x 4 d-blocks), swapped operands
// so softmax row-reduce is in-lane regs + shfl_xor(16/32); P -> bf16 via
// per-wave LDS transpose (C-layout write, A-layout ds_read_b128, same-wave so
// no barrier); PV = mfma(P, V^T) over 7 d-tiles (d<112 covers D=100).
// Lane roles: qi=l&15, g=l>>4. Scores: lane holds S[key=4g+r][q=qi].
// O-frag: lane holds O[q=4g+r][d=dt*16+qi].
__global__ __launch_bounds__(256) void attn_kernel(const bf16* __restrict__ Qp,
    const bf16* __restrict__ Kp, const bf16* __restrict__ VT, float* __restrict__ AO){
  __shared__ uint32 pshare[4*320];     // 4 waves x [16 q][20 dwords pad]
  const float NEGINF = -__builtin_inff();
  int bid = blockIdx.x;
  int xcd = bid & 7, idx = bid >> 3;
  int bh  = xcd*4 + (idx >> 5);        // XCD owns 4 heads -> K/V L2-local
  int qb  = 31 - (idx & 31);           // heavy (high-q) blocks dispatch first
  int tid = threadIdx.x;
  int w = tid >> 6, l = tid & 63;
  int g = l >> 4, qi = l & 15;
  int q0 = qb*64 + w*16;

  const bf16* Qrow  = Qp + ((size_t)bh*T_ + q0 + qi)*DP + g*8;
  const bf16* Krow  = Kp + ((size_t)bh*T_ + qi)*DP + g*8;     // + key*DP
  const bf16* Vbase = VT + (size_t)bh*DP*T_ + g*8;            // + d*T_ + k0

  short8 qf[4];
  #pragma unroll
  for (int db=0; db<4; ++db)
    qf[db] = *reinterpret_cast<const short8*>(Qrow + db*32);

  f32x4 acc[7];
  #pragma unroll
  for (int dt=0; dt<7; ++dt) acc[dt] = (f32x4){0.f,0.f,0.f,0.f};
  float m = NEGINF, lr = 0.f;

  uint32* pbase = &pshare[w*320 + qi*20];
  int qglob = q0 + qi;
  int nch = ((q0 + 15) >> 5) + 1;

  for (int j = 0; j < nch; ++j){
    int k0 = j << 5;
    // ---- S^T tiles: C[key][q], key = k0 + 16t + 4g + r, q = qi ----
    const bf16* kp0 = Krow + (size_t)k0*DP;
    f32x4 s0 = (f32x4){0.f,0.f,0.f,0.f};
    f32x4 s1 = (f32x4){0.f,0.f,0.f,0.f};
    #pragma unroll
    for (int db=0; db<4; ++db){
      short8 kf = *reinterpret_cast<const short8*>(kp0 + db*32);
      s0 = __builtin_amdgcn_mfma_f32_16x16x32_bf16(kf, qf[db], s0, 0, 0, 0);
    }
    #pragma unroll
    for (int db=0; db<4; ++db){
      short8 kf = *reinterpret_cast<const short8*>(kp0 + 16*DP + db*32);
      s1 = __builtin_amdgcn_mfma_f32_16x16x32_bf16(kf, qf[db], s1, 0, 0, 0);
    }
    // ---- mask + online softmax (per q=qi; replicated across 4 groups) ----
    float p0[4], p1[4];
    float cmax = NEGINF;
    #pragma unroll
    for (int r=0; r<4; ++r){
      int key = k0 + 4*g + r;
      float v0 = s0[r]*0.1f; if (key      > qglob) v0 = NEGINF;
      float v1 = s1[r]*0.1f; if (key + 16 > qglob) v1 = NEGINF;
      p0[r]=v0; p1[r]=v1;
      cmax = fmaxf(cmax, fmaxf(v0, v1));
    }
    cmax = fmaxf(cmax, __shfl_xor(cmax, 16));
    cmax = fmaxf(cmax, __shfl_xor(cmax, 32));
    float mnew = fmaxf(m, cmax);
    float scale = __expf(m - mnew);    // first chunk: exp(-inf)=0
    m = mnew;
    float rs = 0.f;
    #pragma unroll
    for (int r=0; r<4; ++r){
      p0[r] = __expf(p0[r] - m);       // masked: exp(-inf)=0
      p1[r] = __expf(p1[r] - m);
      rs += p0[r] + p1[r];
    }
    rs += __shfl_xor(rs, 16);
    rs += __shfl_xor(rs, 32);
    lr = lr*scale + rs;
    // per-O-row rescale: O rows are q=4g+r -> fetch their scale (lane 20g+r)
    float scr[4];
    #pragma unroll
    for (int r=0; r<4; ++r) scr[r] = __shfl(scale, 20*g + r);
    #pragma unroll
    for (int dt=0; dt<7; ++dt){
      acc[dt][0]*=scr[0]; acc[dt][1]*=scr[1]; acc[dt][2]*=scr[2]; acc[dt][3]*=scr[3];
    }
    // ---- P transpose via LDS: write [q=qi][key/2], read A-frag [q][8g..8g+7]
    pbase[    2*g] = pk2(p0[0], p0[1]);
    pbase[    2*g+1] = pk2(p0[2], p0[3]);
    pbase[8 + 2*g] = pk2(p1[0], p1[1]);
    pbase[8 + 2*g+1] = pk2(p1[2], p1[3]);
    short8 pa = *reinterpret_cast<const short8*>(pbase + 4*g);  // same-wave RAW
    // ---- PV: O[q][d] += P[q][key] * V[key][d] ----
    const bf16* vp = Vbase + k0;
    #pragma unroll
    for (int dt=0; dt<7; ++dt){
      short8 vf = *reinterpret_cast<const short8*>(vp + (size_t)(dt*16 + qi)*T_);
      acc[dt] = __builtin_amdgcn_mfma_f32_16x16x32_bf16(pa, vf, acc[dt], 0, 0, 0);
    }
  }
  // ---- epilogue: divide by lr (per O-row) and store d<100 ----
  float inv = 1.f / lr;
  float invr[4];
  #pragma unroll
  for (int r=0; r<4; ++r) invr[r] = __shfl(inv, 20*g + r);
  int b = bh >> 2, h = bh & 3;
  #pragma unroll
  for (int dt=0; dt<7; ++dt){
    int d = dt*16 + qi;
    if (d < D_){
      #pragma unroll
      for (int r=0; r<4; ++r){
        size_t row = (size_t)(b*T_) + q0 + 4*g + r;
        AO[row*C_ + h*D_ + d] = acc[dt][r] * invr[r];
      }
    }
  }
}

// ---------------------------------------------------------------------------
// out = AO @ Wo^T + bo (all fp32), WoT pre-transposed so weight reads
// coalesce over n.
__global__ __launch_bounds__(256) void out_proj_kernel(const float* __restrict__ AO,
    const float* __restrict__ WoT, const float* __restrict__ bo, float* __restrict__ out){
  __shared__ __align__(16) float as[C_ * TM];    // [c][t]
  int bid = blockIdx.x;
  int b = bid / (T_/TM);
  int t0 = (bid % (T_/TM)) * TM;
  int tid = threadIdx.x;
  for (int i = tid; i < TM*C_; i += 256){
    int t = i / C_, c = i % C_;
    as[c*TM + t] = AO[(size_t)(b*T_ + t0 + t)*C_ + c];
  }
  __syncthreads();
  float acc0[TM], acc1[TM];
  #pragma unroll
  for (int t=0;t<TM;++t){ acc0[t]=0.f; acc1[t]=0.f; }
  int n0 = tid;
  int n1 = tid + 256;
  bool v1 = (n1 < C_);
  int n1c = v1 ? n1 : 0;
  for (int c=0;c<C_;++c){
    float w0 = WoT[c*C_ + n0];
    float w1 = WoT[c*C_ + n1c];
    float4 a0 = *reinterpret_cast<const float4*>(&as[c*TM]);
    float4 a1 = *reinterpret_cast<const float4*>(&as[c*TM+4]);
    float av[8] = {a0.x,a0.y,a0.z,a0.w,a1.x,a1.y,a1.z,a1.w};
    #pragma unroll
    for (int t=0;t<TM;++t){
      acc0[t] = fmaf(av[t], w0, acc0[t]);
      acc1[t] = fmaf(av[t], w1, acc1[t]);
    }
  }
  float b0 = bo[n0];
  float b1 = bo[n1c];
  #pragma unroll
  for (int t=0;t<TM;++t){
    size_t row = (size_t)(b*T_ + t0 + t)*C_;
    out[row + n0] = acc0[t] + b0;
    if (v1) out[row + n1] = acc1[t] + b1;
  }
}

// ---------------------------------------------------------------------------
extern "C" void kernel_launch(void* const* d_in, const int* in_sizes, int n_in,
                              void* d_out, int out_size, void* d_ws, size_t ws_size,
                              hipStream_t stream){
  const float* x  = (const float*)d_in[0];
  const float* Wq = (const float*)d_in[1];
  const float* Wk = (const float*)d_in[2];
  const float* Wv = (const float*)d_in[3];
  const float* Wo = (const float*)d_in[4];
  const float* bo = (const float*)d_in[5];

  constexpr size_t NBH  = (size_t)B_*H_;                 // 32
  constexpr size_t NPAD = NBH*T_*DP;                     // 8,388,608 elems
  constexpr size_t OFF_QP  = 0;
  constexpr size_t OFF_KP  = OFF_QP + NPAD*2;
  constexpr size_t OFF_VT  = OFF_KP + NPAD*2;
  constexpr size_t OFF_AO  = OFF_VT + NPAD*2;
  constexpr size_t OFF_WOT = OFF_AO + (size_t)B_*T_*C_*4;
  constexpr size_t TOTAL   = OFF_WOT + (size_t)C_*C_*4;  // ~77.2 MB
  if (ws_size < TOTAL) return;   // visible failure signature (output stays zero)

  char* ws = (char*)d_ws;
  bf16*  Qp   = (bf16*)(ws + OFF_QP);
  bf16*  Kp   = (bf16*)(ws + OFF_KP);
  bf16*  VTp  = (bf16*)(ws + OFF_VT);
  float* AO   = (float*)(ws + OFF_AO);
  float* WoT  = (float*)(ws + OFF_WOT);
  float* out  = (float*)d_out;

  // Zero Qp once per call: its d>=100 pad must be exact 0 so QK over padded
  // dims contributes 0 (K/V pads can stay garbage: 0 * x == 0, unused cols).
  hipMemsetAsync(Qp, 0, NPAD*2, stream);
  wo_prep_kernel<<<625, 256, 0, stream>>>(Wo, WoT);
  qkv_proj_kernel<<<B_*(T_/TM), 256, 0, stream>>>(x, Wq, Wk, Wv, Qp, Kp, VTp);
  attn_kernel<<<NBH*32, 256, 0, stream>>>(Qp, Kp, VTp, AO);
  out_proj_kernel<<<B_*(T_/TM), 256, 0, stream>>>(AO, WoT, bo, out);
}

// Round 6
// 548.126 us; speedup vs baseline: 11.6132x; 1.2365x over previous
//
#include <hip/hip_runtime.h>
#include <hip/hip_bf16.h>

#define B_ 8
#define T_ 2048
#define C_ 400
#define H_ 4
#define D_ 100
#define DP 128
#define TM 8

typedef __hip_bfloat16 bf16;
typedef unsigned int uint32;
typedef __attribute__((ext_vector_type(8))) short short8;
typedef __attribute__((ext_vector_type(4))) float f32x4;

__device__ __forceinline__ float bf2f(bf16 v){ return __bfloat162float(v); }
__device__ __forceinline__ bf16 f2bf(float f){ return __float2bfloat16(f); }
__device__ __forceinline__ unsigned short bfbits(float f){
  bf16 h = f2bf(f);
  return __builtin_bit_cast(unsigned short, h);
}
__device__ __forceinline__ uint32 pk2(float a, float b){
  return (uint32)bfbits(a) | ((uint32)bfbits(b) << 16);
}
__device__ __forceinline__ void gl_lds16(const char* gsrc, char* ldst){
  __builtin_amdgcn_global_load_lds(
      (const __attribute__((address_space(1))) unsigned int*)gsrc,
      (__attribute__((address_space(3))) unsigned int*)ldst, 16, 0, 0);
}

// ---------------------------------------------------------------------------
// Wo^T fp32 (so out-proj weight reads are coalesced over n)
__global__ void wo_prep_kernel(const float* __restrict__ Wo, float* __restrict__ WoT){
  int i = blockIdx.x * blockDim.x + threadIdx.x;
  if (i < C_*C_){
    int n = i / C_, c = i % C_;
    WoT[c*C_ + n] = Wo[i];
  }
}

// ---------------------------------------------------------------------------
// QKV projection (fp32 in, fp32 accum). Outputs (all bf16, D padded to 128):
//   Qp, Kp: [bh][T][DP] t-major  (MFMA A/B fragment rows; Qp pad pre-zeroed)
//   VT:     [bh][DP][T] d-major  (MFMA B fragment for PV)
__global__ __launch_bounds__(256) void qkv_proj_kernel(const float* __restrict__ x,
    const float* __restrict__ Wq, const float* __restrict__ Wk, const float* __restrict__ Wv,
    bf16* __restrict__ Qp, bf16* __restrict__ Kp, bf16* __restrict__ VT){
  __shared__ __align__(16) float xs[C_ * TM];   // [c][t]
  int bid = blockIdx.x;
  int b = bid / (T_/TM);
  int t0 = (bid % (T_/TM)) * TM;
  int tid = threadIdx.x;
  for (int i = tid; i < TM*C_; i += 256){
    int t = i / C_, c = i % C_;
    xs[c*TM + t] = x[(size_t)(b*T_ + t0 + t)*C_ + c];
  }
  __syncthreads();

  float acc[5][TM];
  #pragma unroll
  for (int s=0;s<5;++s){
    #pragma unroll
    for (int t=0;t<TM;++t) acc[s][t]=0.f;
  }
  // output slot o = p*400 + h*100 + d  (p: 0=q,1=k,2=v), o = s*256+tid
  const float* wptr[5];
  int pp[5], dd[5], hh[5]; bool val[5];
  #pragma unroll
  for (int s=0;s<5;++s){
    int o = s*256 + tid;
    val[s] = (o < 3*H_*D_);
    int oc = val[s] ? o : 0;
    int p = oc / (H_*D_), rem = oc % (H_*D_);
    int h = rem / D_, d = rem % D_;
    const float* W = (p==0) ? Wq : (p==1) ? Wk : Wv;
    wptr[s] = W + h*(C_*D_) + d;
    pp[s]=p; hh[s]=h; dd[s]=d;
  }
  for (int c=0;c<C_;++c){
    float wv[5];
    #pragma unroll
    for (int s=0;s<5;++s) wv[s] = wptr[s][c*D_];
    float4 x0 = *reinterpret_cast<const float4*>(&xs[c*TM]);
    float4 x1 = *reinterpret_cast<const float4*>(&xs[c*TM+4]);
    float xv[8] = {x0.x,x0.y,x0.z,x0.w,x1.x,x1.y,x1.z,x1.w};
    #pragma unroll
    for (int t=0;t<TM;++t){
      #pragma unroll
      for (int s=0;s<5;++s) acc[s][t] = fmaf(xv[t], wv[s], acc[s][t]);
    }
  }
  #pragma unroll
  for (int s=0;s<5;++s){
    if (!val[s]) continue;
    int p=pp[s], h=hh[s], d=dd[s];
    size_t bh = (size_t)b*H_ + h;
    if (p == 2){
      unsigned int u[4];
      #pragma unroll
      for (int t2=0; t2<4; ++t2)
        u[t2] = pk2(acc[s][2*t2], acc[s][2*t2+1]);
      bf16* base = VT + (bh*DP + d)*T_ + t0;
      *reinterpret_cast<uint4*>(base) = make_uint4(u[0],u[1],u[2],u[3]);  // 16B aligned
    } else {
      bf16* dst = (p==0 ? Qp : Kp) + (bh*T_ + t0)*DP + d;
      #pragma unroll
      for (int t=0;t<TM;++t)
        dst[(size_t)t*DP] = f2bf(acc[s][t]);
    }
  }
}

// ---------------------------------------------------------------------------
// MFMA flash attention v3: 4 waves/block, wave owns 16 q-rows, 64-key chunks.
// K-tile (64x128 bf16 = 16KB) staged in LDS double-buffered via
// global_load_lds(16B) with PRE-SWIZZLED global source (T21): LDS dest linear,
// src byte col ^= (row&15)<<4; ds_read_b128 applies the same XOR -> 4 lanes
// per 16B slot = conflict-free minimum. Stage of chunk j+1 issued before
// compute of chunk j; __syncthreads (vmcnt drain) at iter end = 2-phase pipe.
// All 4 waves need exactly qb+1 chunks (q's share a 64-block) -> no waste;
// causal mask only in last chunk (wave-uniform branch).
// S^T = mfma(K,Q): lane(g,qi) holds S[key=kt*16+4g+r][q=qi]; softmax in-lane
// + shfl_xor(16/32); P->bf16 via per-wave LDS bounce; PV = mfma(P, V^T) from
// global-L2 V (independent loads, prefetched under QK by compiler).
__global__ __launch_bounds__(256) void attn_kernel(const bf16* __restrict__ Qp,
    const bf16* __restrict__ Kp, const bf16* __restrict__ VT, float* __restrict__ AO){
  __shared__ __align__(16) char ktile[2][16384];
  __shared__ __align__(16) uint32 pshare[4*16*36];   // 4 waves x 16 q x (32+4 pad)
  const float NEGINF = -__builtin_inff();
  int bid = blockIdx.x;
  int xcd = bid & 7, idx = bid >> 3;
  int bh  = xcd*4 + (idx >> 5);        // XCD owns 4 heads -> K/V L2-local
  int qb  = 31 - (idx & 31);           // heavy (high-q) blocks dispatch first
  int tid = threadIdx.x;
  int w = tid >> 6, l = tid & 63;
  int g = l >> 4, qi = l & 15;
  int q0 = qb*64 + w*16;

  const bf16* Qrow  = Qp + ((size_t)bh*T_ + q0 + qi)*DP + g*8;
  const char* Kg    = (const char*)(Kp + (size_t)bh*T_*DP);   // rows of 256B
  const bf16* Vbase = VT + (size_t)bh*DP*T_;                  // row d stride T_

  short8 qf[4];
  #pragma unroll
  for (int ks=0; ks<4; ++ks)
    qf[ks] = *reinterpret_cast<const short8*>(Qrow + ks*32);

  f32x4 acc[7];
  #pragma unroll
  for (int dt=0; dt<7; ++dt) acc[dt] = (f32x4){0.f,0.f,0.f,0.f};
  float m = NEGINF, lr = 0.f;

  uint32* pbase = &pshare[(w*16 + qi)*36];
  int qglob = q0 + qi;
  int nch = qb + 1;

  // wave w stages rows [w*16, w*16+16) of the tile: 4 x 64 lanes x 16B = 4KB
  int st_off0 = w*4096 + l*16;
  #define STAGE(J, BUF) { int k0s = (J) << 6;                                   \
    _Pragma("unroll")                                                           \
    for (int it=0; it<4; ++it){                                                 \
      int off = st_off0 + it*1024;                                              \
      int row = off >> 8;                                                       \
      int cb  = off & 255;                                                      \
      gl_lds16(Kg + (size_t)(k0s + row)*256 + (cb ^ ((row&15)<<4)),             \
               &ktile[BUF][w*4096 + it*1024]); } }

  STAGE(0, 0)
  __syncthreads();

  for (int j = 0; j < nch; ++j){
    int k0 = j << 6;
    int cur = j & 1;
    if (j + 1 < nch) STAGE(j+1, cur^1)
    const char* kb = ktile[cur];
    // ---- S^T tiles: 4 key-tiles x 4 k-slabs ----
    f32x4 st[4];
    #pragma unroll
    for (int kt=0; kt<4; ++kt){
      f32x4 s = (f32x4){0.f,0.f,0.f,0.f};
      #pragma unroll
      for (int ks=0; ks<4; ++ks){
        short8 kf = *reinterpret_cast<const short8*>(
            kb + (kt*16 + qi)*256 + ((ks*64 + g*16) ^ (qi<<4)));
        s = __builtin_amdgcn_mfma_f32_16x16x32_bf16(kf, qf[ks], s, 0, 0, 0);
      }
      st[kt] = s;
    }
    // ---- mask (last chunk only) + online softmax ----
    float p[4][4];
    float cmax = NEGINF;
    if (j == nch - 1){
      #pragma unroll
      for (int kt=0; kt<4; ++kt)
        #pragma unroll
        for (int r=0; r<4; ++r){
          int key = k0 + kt*16 + 4*g + r;
          float v = st[kt][r]*0.1f; if (key > qglob) v = NEGINF;
          p[kt][r] = v; cmax = fmaxf(cmax, v);
        }
    } else {
      #pragma unroll
      for (int kt=0; kt<4; ++kt)
        #pragma unroll
        for (int r=0; r<4; ++r){
          float v = st[kt][r]*0.1f;
          p[kt][r] = v; cmax = fmaxf(cmax, v);
        }
    }
    cmax = fmaxf(cmax, __shfl_xor(cmax, 16));
    cmax = fmaxf(cmax, __shfl_xor(cmax, 32));
    float mnew = fmaxf(m, cmax);
    float scale = __expf(m - mnew);    // first chunk: exp(-inf)=0
    m = mnew;
    float rs = 0.f;
    #pragma unroll
    for (int kt=0; kt<4; ++kt)
      #pragma unroll
      for (int r=0; r<4; ++r){
        p[kt][r] = __expf(p[kt][r] - m);   // masked: exp(-inf)=0
        rs += p[kt][r];
      }
    rs += __shfl_xor(rs, 16);
    rs += __shfl_xor(rs, 32);
    lr = lr*scale + rs;
    // per-O-row rescale: O rows are q=4g+r -> fetch their scale
    float scr[4];
    #pragma unroll
    for (int r=0; r<4; ++r) scr[r] = __shfl(scale, 20*g + r);
    #pragma unroll
    for (int dt=0; dt<7; ++dt){
      acc[dt][0]*=scr[0]; acc[dt][1]*=scr[1]; acc[dt][2]*=scr[2]; acc[dt][3]*=scr[3];
    }
    // ---- P bounce: write [q=qi][key/2 dwords], read A-frags ----
    #pragma unroll
    for (int kt=0; kt<4; ++kt){
      pbase[kt*8 + 2*g    ] = pk2(p[kt][0], p[kt][1]);
      pbase[kt*8 + 2*g + 1] = pk2(p[kt][2], p[kt][3]);
    }
    // ---- PV: O[q][d] += P[q][key] * V[key][d], 2 k-slabs x 7 d-tiles ----
    #pragma unroll
    for (int ks=0; ks<2; ++ks){
      short8 pa = *reinterpret_cast<const short8*>(pbase + 16*ks + 4*g); // same-wave RAW
      const bf16* vp = Vbase + k0 + ks*32 + g*8;
      #pragma unroll
      for (int dt=0; dt<7; ++dt){
        short8 vf = *reinterpret_cast<const short8*>(vp + (size_t)(dt*16 + qi)*T_);
        acc[dt] = __builtin_amdgcn_mfma_f32_16x16x32_bf16(pa, vf, acc[dt], 0, 0, 0);
      }
    }
    __syncthreads();   // drains vmcnt (next K-tile staged) + protects reuse
  }
  // ---- epilogue: divide by lr (per O-row) and store d<100 ----
  float inv = 1.f / lr;
  float invr[4];
  #pragma unroll
  for (int r=0; r<4; ++r) invr[r] = __shfl(inv, 20*g + r);
  int b = bh >> 2, h = bh & 3;
  #pragma unroll
  for (int dt=0; dt<7; ++dt){
    int d = dt*16 + qi;
    if (d < D_){
      #pragma unroll
      for (int r=0; r<4; ++r){
        size_t row = (size_t)(b*T_) + q0 + 4*g + r;
        AO[row*C_ + h*D_ + d] = acc[dt][r] * invr[r];
      }
    }
  }
}

// ---------------------------------------------------------------------------
// out = AO @ Wo^T + bo (all fp32), WoT pre-transposed so weight reads
// coalesce over n.
__global__ __launch_bounds__(256) void out_proj_kernel(const float* __restrict__ AO,
    const float* __restrict__ WoT, const float* __restrict__ bo, float* __restrict__ out){
  __shared__ __align__(16) float as[C_ * TM];    // [c][t]
  int bid = blockIdx.x;
  int b = bid / (T_/TM);
  int t0 = (bid % (T_/TM)) * TM;
  int tid = threadIdx.x;
  for (int i = tid; i < TM*C_; i += 256){
    int t = i / C_, c = i % C_;
    as[c*TM + t] = AO[(size_t)(b*T_ + t0 + t)*C_ + c];
  }
  __syncthreads();
  float acc0[TM], acc1[TM];
  #pragma unroll
  for (int t=0;t<TM;++t){ acc0[t]=0.f; acc1[t]=0.f; }
  int n0 = tid;
  int n1 = tid + 256;
  bool v1 = (n1 < C_);
  int n1c = v1 ? n1 : 0;
  for (int c=0;c<C_;++c){
    float w0 = WoT[c*C_ + n0];
    float w1 = WoT[c*C_ + n1c];
    float4 a0 = *reinterpret_cast<const float4*>(&as[c*TM]);
    float4 a1 = *reinterpret_cast<const float4*>(&as[c*TM+4]);
    float av[8] = {a0.x,a0.y,a0.z,a0.w,a1.x,a1.y,a1.z,a1.w};
    #pragma unroll
    for (int t=0;t<TM;++t){
      acc0[t] = fmaf(av[t], w0, acc0[t]);
      acc1[t] = fmaf(av[t], w1, acc1[t]);
    }
  }
  float b0 = bo[n0];
  float b1 = bo[n1c];
  #pragma unroll
  for (int t=0;t<TM;++t){
    size_t row = (size_t)(b*T_ + t0 + t)*C_;
    out[row + n0] = acc0[t] + b0;
    if (v1) out[row + n1] = acc1[t] + b1;
  }
}

// ---------------------------------------------------------------------------
extern "C" void kernel_launch(void* const* d_in, const int* in_sizes, int n_in,
                              void* d_out, int out_size, void* d_ws, size_t ws_size,
                              hipStream_t stream){
  const float* x  = (const float*)d_in[0];
  const float* Wq = (const float*)d_in[1];
  const float* Wk = (const float*)d_in[2];
  const float* Wv = (const float*)d_in[3];
  const float* Wo = (const float*)d_in[4];
  const float* bo = (const float*)d_in[5];

  constexpr size_t NBH  = (size_t)B_*H_;                 // 32
  constexpr size_t NPAD = NBH*T_*DP;                     // 8,388,608 elems
  constexpr size_t OFF_QP  = 0;
  constexpr size_t OFF_KP  = OFF_QP + NPAD*2;
  constexpr size_t OFF_VT  = OFF_KP + NPAD*2;
  constexpr size_t OFF_AO  = OFF_VT + NPAD*2;
  constexpr size_t OFF_WOT = OFF_AO + (size_t)B_*T_*C_*4;
  constexpr size_t TOTAL   = OFF_WOT + (size_t)C_*C_*4;  // ~77.2 MB
  if (ws_size < TOTAL) return;   // visible failure signature (output stays zero)

  char* ws = (char*)d_ws;
  bf16*  Qp   = (bf16*)(ws + OFF_QP);
  bf16*  Kp   = (bf16*)(ws + OFF_KP);
  bf16*  VTp  = (bf16*)(ws + OFF_VT);
  float* AO   = (float*)(ws + OFF_AO);
  float* WoT  = (float*)(ws + OFF_WOT);
  float* out  = (float*)d_out;

  // Zero Qp once per call: its d>=100 pad must be exact 0 so QK over padded
  // dims contributes 0 (K/V pads can stay garbage: 0 * x == 0, unused cols).
  hipMemsetAsync(Qp, 0, NPAD*2, stream);
  wo_prep_kernel<<<625, 256, 0, stream>>>(Wo, WoT);
  qkv_proj_kernel<<<B_*(T_/TM), 256, 0, stream>>>(x, Wq, Wk, Wv, Qp, Kp, VTp);
  attn_kernel<<<NBH*32, 256, 0, stream>>>(Qp, Kp, VTp, AO);
  out_proj_kernel<<<B_*(T_/TM), 256, 0, stream>>>(AO, WoT, bo, out);
}

// Round 7
// 260.082 us; speedup vs baseline: 24.4750x; 2.1075x over previous
//
#include <hip/hip_runtime.h>
#include <hip/hip_bf16.h>

#define B_ 8
#define T_ 2048
#define C_ 400
#define H_ 4
#define D_ 100
#define DP 128
#define KP 416   // C_ padded to 13*32
#define KPB 832  // KP bytes (bf16)

typedef __hip_bfloat16 bf16;
typedef unsigned int uint32;
typedef __attribute__((ext_vector_type(8))) short short8;
typedef __attribute__((ext_vector_type(4))) float f32x4;

__device__ __forceinline__ float bf2f(bf16 v){ return __bfloat162float(v); }
__device__ __forceinline__ bf16 f2bf(float f){ return __float2bfloat16(f); }
__device__ __forceinline__ unsigned short bfbits(float f){
  bf16 h = f2bf(f);
  return __builtin_bit_cast(unsigned short, h);
}
__device__ __forceinline__ uint32 pk2(float a, float b){
  return (uint32)bfbits(a) | ((uint32)bfbits(b) << 16);
}
__device__ __forceinline__ void gl_lds16(const char* gsrc, char* ldst){
  __builtin_amdgcn_global_load_lds(
      (const __attribute__((address_space(1))) unsigned int*)gsrc,
      (__attribute__((address_space(3))) unsigned int*)ldst, 16, 0, 0);
}

// ---------------------------------------------------------------------------
// x fp32 [16384][400] -> xb bf16 [16384][416], pad cols zero. uint4 writes.
__global__ __launch_bounds__(256) void conv_x_kernel(const float* __restrict__ x,
    bf16* __restrict__ xb){
  int i = blockIdx.x*256 + threadIdx.x;          // over 16384*52
  if (i >= 16384*52) return;
  int c8 = i % 52, t = i / 52;
  uint32 u[4];
  if (c8 < 50){
    const float* src = x + (size_t)t*C_ + c8*8;
    #pragma unroll
    for (int k=0;k<4;++k) u[k] = pk2(src[2*k], src[2*k+1]);
  } else {
    u[0]=u[1]=u[2]=u[3]=0;
  }
  *reinterpret_cast<uint4*>((char*)xb + (size_t)t*KPB + c8*16) = make_uint4(u[0],u[1],u[2],u[3]);
}

// Wq/Wk/Wv [H][C][D] fp32 -> WT [12][128][416] bf16: WT[p*4+h][d][c] = W_p[h][c][d],
// zero-padded (d>=100 or c>=400). Dest-coalesced; strided source absorbed by L2.
__global__ __launch_bounds__(256) void prep_wqkv_kernel(const float* __restrict__ Wq,
    const float* __restrict__ Wk, const float* __restrict__ Wv, bf16* __restrict__ WT){
  int i = blockIdx.x*256 + threadIdx.x;          // over 12*128*416
  if (i >= 12*128*KP) return;
  int c = i % KP, n = (i/KP) & 127, group = i/(KP*128);
  int p = group >> 2, h = group & 3;
  float v = 0.f;
  if (n < D_ && c < C_){
    const float* W = (p==0)?Wq:(p==1)?Wk:Wv;
    v = W[((size_t)h*C_ + c)*D_ + n];
  }
  WT[i] = f2bf(v);
}

// Wo [400][400] fp32 -> WoB [512][416] bf16 zero-padded (rows of W^T layout).
__global__ __launch_bounds__(256) void prep_wo_kernel(const float* __restrict__ Wo,
    bf16* __restrict__ WoB){
  int i = blockIdx.x*256 + threadIdx.x;          // over 512*416
  if (i >= 512*KP) return;
  int c = i % KP, n = i / KP;
  float v = (n < C_ && c < C_) ? Wo[(size_t)n*C_ + c] : 0.f;
  WoB[i] = f2bf(v);
}

// AOb pad cols 400..415 = 0 (once per call; attn writes only cols<400).
__global__ __launch_bounds__(256) void zero_aopad_kernel(bf16* __restrict__ AOb){
  int i = blockIdx.x*256 + threadIdx.x;          // over 16384*2
  if (i >= 16384*2) return;
  int row = i >> 1, half = i & 1;
  *reinterpret_cast<uint4*>((char*)AOb + (size_t)row*KPB + 800 + half*16) = make_uint4(0,0,0,0);
}

// ---------------------------------------------------------------------------
// QKV MFMA GEMM: C = xb[16384][416] * WT_g^T per (p,h) group (N=128=DP).
// 128x128 tile, 4 waves (wave: 32 rows x 128 cols, acc[2][8]), BK=32,
// A+B staged via global_load_lds(16B), double-buffered (32KB LDS).
// p<2: acc = mfma(af,bf) -> C[t][d] stored to Qp/Kp [bh][t][128] (pads = real
// zeros -> no Qp memset). p==2: acc = mfma(bf,af) -> C[d][t] = V^T stored
// t-coalesced to VT [bh][128][T].
// bid: XCD-chunked: each XCD owns 16 m-tiles x 12 groups -> x set 1.7MB L2-res.
__global__ __launch_bounds__(256) void qkv_gemm_kernel(const bf16* __restrict__ xb,
    const bf16* __restrict__ WT, bf16* __restrict__ Qp, bf16* __restrict__ Kp,
    bf16* __restrict__ VT){
  __shared__ __align__(16) char xs[2][8192];
  __shared__ __align__(16) char wsh[2][8192];
  int bid = blockIdx.x;
  int xcd = bid & 7, idx = bid >> 3;             // idx 0..191
  int mb = xcd*16 + idx/12;
  int group = idx % 12;
  int p = group >> 2, h = group & 3;
  int t0 = mb * 128;
  int tid = threadIdx.x;
  int w = tid >> 6, l = tid & 63, g = l >> 4, qi = l & 15;
  const char* xg = (const char*)xb + (size_t)t0*KPB;
  const char* wg = (const char*)WT + (size_t)group*128*KPB;
  int srow = tid >> 2, sseg = tid & 3;

  #define GSTAGE(J, BUF) {                                                     \
    int kc2 = (J)*64;                                                          \
    _Pragma("unroll")                                                          \
    for (int r2=0;r2<2;++r2)                                                   \
      gl_lds16(xg + (size_t)(srow + r2*64)*KPB + kc2 + sseg*16,                \
               &xs[BUF][tid*16 + r2*4096]);                                    \
    _Pragma("unroll")                                                          \
    for (int r2=0;r2<2;++r2)                                                   \
      gl_lds16(wg + (size_t)(srow + r2*64)*KPB + kc2 + sseg*16,                \
               &wsh[BUF][tid*16 + r2*4096]); }

  f32x4 acc[2][8];
  #pragma unroll
  for (int mt=0;mt<2;++mt)
    #pragma unroll
    for (int nt=0;nt<8;++nt) acc[mt][nt] = (f32x4){0.f,0.f,0.f,0.f};

  GSTAGE(0, 0)
  __syncthreads();
  for (int j = 0; j < 13; ++j){
    int cur = j & 1;
    if (j < 12) GSTAGE(j+1, cur^1)
    short8 af[2];
    #pragma unroll
    for (int mt=0;mt<2;++mt)
      af[mt] = *reinterpret_cast<const short8*>(&xs[cur][(w*32 + mt*16 + qi)*64 + g*16]);
    short8 bfr[8];
    #pragma unroll
    for (int nt=0;nt<8;++nt)
      bfr[nt] = *reinterpret_cast<const short8*>(&wsh[cur][(nt*16 + qi)*64 + g*16]);
    if (p < 2){
      #pragma unroll
      for (int mt=0;mt<2;++mt)
        #pragma unroll
        for (int nt=0;nt<8;++nt)
          acc[mt][nt] = __builtin_amdgcn_mfma_f32_16x16x32_bf16(af[mt], bfr[nt], acc[mt][nt], 0,0,0);
    } else {
      #pragma unroll
      for (int mt=0;mt<2;++mt)
        #pragma unroll
        for (int nt=0;nt<8;++nt)
          acc[mt][nt] = __builtin_amdgcn_mfma_f32_16x16x32_bf16(bfr[nt], af[mt], acc[mt][nt], 0,0,0);
    }
    __syncthreads();
  }

  int b = t0 >> 11, tloc0 = t0 & 2047;
  size_t bh = (size_t)b*H_ + h;
  if (p < 2){
    bf16* dst = (p==0 ? Qp : Kp) + (bh*T_ + tloc0)*DP;
    #pragma unroll
    for (int mt=0;mt<2;++mt)
      #pragma unroll
      for (int r=0;r<4;++r){
        int tr = w*32 + mt*16 + 4*g + r;
        #pragma unroll
        for (int nt=0;nt<8;++nt)
          dst[(size_t)tr*DP + nt*16 + qi] = f2bf(acc[mt][nt][r]);
      }
  } else {
    bf16* dstv = VT + bh*DP*T_ + tloc0;
    #pragma unroll
    for (int nt=0;nt<8;++nt)
      #pragma unroll
      for (int r=0;r<4;++r){
        int d = nt*16 + 4*g + r;
        #pragma unroll
        for (int mt=0;mt<2;++mt)
          dstv[(size_t)d*T_ + w*32 + mt*16 + qi] = f2bf(acc[mt][nt][r]);
      }
  }
  #undef GSTAGE
}

// ---------------------------------------------------------------------------
// Out-proj MFMA GEMM: out[t][n] = AOb[16384][416] . WoB[n][416] + bo[n], fp32
// stores, n<400 masked (wave-uniform per nt). Same 128x128/BK=32 skeleton.
__global__ __launch_bounds__(256) void out_gemm_kernel(const bf16* __restrict__ AOb,
    const bf16* __restrict__ WoB, const float* __restrict__ bo, float* __restrict__ out){
  __shared__ __align__(16) char xs[2][8192];
  __shared__ __align__(16) char wsh[2][8192];
  int bid = blockIdx.x;
  int xcd = bid & 7, idx = bid >> 3;             // idx 0..63
  int mb = xcd*16 + idx/4;
  int nb = idx & 3;
  int t0 = mb * 128, n0 = nb * 128;
  int tid = threadIdx.x;
  int w = tid >> 6, l = tid & 63, g = l >> 4, qi = l & 15;
  const char* xg = (const char*)AOb + (size_t)t0*KPB;
  const char* wg = (const char*)WoB + (size_t)n0*KPB;
  int srow = tid >> 2, sseg = tid & 3;

  #define GSTAGE(J, BUF) {                                                     \
    int kc2 = (J)*64;                                                          \
    _Pragma("unroll")                                                          \
    for (int r2=0;r2<2;++r2)                                                   \
      gl_lds16(xg + (size_t)(srow + r2*64)*KPB + kc2 + sseg*16,                \
               &xs[BUF][tid*16 + r2*4096]);                                    \
    _Pragma("unroll")                                                          \
    for (int r2=0;r2<2;++r2)                                                   \
      gl_lds16(wg + (size_t)(srow + r2*64)*KPB + kc2 + sseg*16,                \
               &wsh[BUF][tid*16 + r2*4096]); }

  f32x4 acc[2][8];
  #pragma unroll
  for (int mt=0;mt<2;++mt)
    #pragma unroll
    for (int nt=0;nt<8;++nt) acc[mt][nt] = (f32x4){0.f,0.f,0.f,0.f};

  GSTAGE(0, 0)
  __syncthreads();
  for (int j = 0; j < 13; ++j){
    int cur = j & 1;
    if (j < 12) GSTAGE(j+1, cur^1)
    short8 af[2];
    #pragma unroll
    for (int mt=0;mt<2;++mt)
      af[mt] = *reinterpret_cast<const short8*>(&xs[cur][(w*32 + mt*16 + qi)*64 + g*16]);
    short8 bfr[8];
    #pragma unroll
    for (int nt=0;nt<8;++nt)
      bfr[nt] = *reinterpret_cast<const short8*>(&wsh[cur][(nt*16 + qi)*64 + g*16]);
    #pragma unroll
    for (int mt=0;mt<2;++mt)
      #pragma unroll
      for (int nt=0;nt<8;++nt)
        acc[mt][nt] = __builtin_amdgcn_mfma_f32_16x16x32_bf16(af[mt], bfr[nt], acc[mt][nt], 0,0,0);
    __syncthreads();
  }

  #pragma unroll
  for (int nt=0;nt<8;++nt){
    if (n0 + nt*16 >= C_) continue;              // wave-uniform (400 % 16 == 0)
    int n = n0 + nt*16 + qi;
    float bv = bo[n];
    #pragma unroll
    for (int mt=0;mt<2;++mt)
      #pragma unroll
      for (int r=0;r<4;++r){
        int tr = w*32 + mt*16 + 4*g + r;
        out[(size_t)(t0 + tr)*C_ + n] = acc[mt][nt][r] + bv;
      }
  }
  #undef GSTAGE
}

// ---------------------------------------------------------------------------
// MFMA flash attention (unchanged from R6 except bf16 AOb output).
__global__ __launch_bounds__(256) void attn_kernel(const bf16* __restrict__ Qp,
    const bf16* __restrict__ Kp, const bf16* __restrict__ VT, bf16* __restrict__ AOb){
  __shared__ __align__(16) char ktile[2][16384];
  __shared__ __align__(16) uint32 pshare[4*16*36];
  const float NEGINF = -__builtin_inff();
  int bid = blockIdx.x;
  int xcd = bid & 7, idx = bid >> 3;
  int bh  = xcd*4 + (idx >> 5);
  int qb  = 31 - (idx & 31);
  int tid = threadIdx.x;
  int w = tid >> 6, l = tid & 63;
  int g = l >> 4, qi = l & 15;
  int q0 = qb*64 + w*16;

  const bf16* Qrow  = Qp + ((size_t)bh*T_ + q0 + qi)*DP + g*8;
  const char* Kg    = (const char*)(Kp + (size_t)bh*T_*DP);
  const bf16* Vbase = VT + (size_t)bh*DP*T_;

  short8 qf[4];
  #pragma unroll
  for (int ks=0; ks<4; ++ks)
    qf[ks] = *reinterpret_cast<const short8*>(Qrow + ks*32);

  f32x4 acc[7];
  #pragma unroll
  for (int dt=0; dt<7; ++dt) acc[dt] = (f32x4){0.f,0.f,0.f,0.f};
  float m = NEGINF, lr = 0.f;

  uint32* pbase = &pshare[(w*16 + qi)*36];
  int qglob = q0 + qi;
  int nch = qb + 1;

  int st_off0 = w*4096 + l*16;
  #define STAGE(J, BUF) { int k0s = (J) << 6;                                   \
    _Pragma("unroll")                                                           \
    for (int it=0; it<4; ++it){                                                 \
      int off = st_off0 + it*1024;                                              \
      int row = off >> 8;                                                       \
      int cb  = off & 255;                                                      \
      gl_lds16(Kg + (size_t)(k0s + row)*256 + (cb ^ ((row&15)<<4)),             \
               &ktile[BUF][w*4096 + it*1024]); } }

  STAGE(0, 0)
  __syncthreads();

  for (int j = 0; j < nch; ++j){
    int k0 = j << 6;
    int cur = j & 1;
    if (j + 1 < nch) STAGE(j+1, cur^1)
    const char* kb = ktile[cur];
    f32x4 st[4];
    #pragma unroll
    for (int kt=0; kt<4; ++kt){
      f32x4 s = (f32x4){0.f,0.f,0.f,0.f};
      #pragma unroll
      for (int ks=0; ks<4; ++ks){
        short8 kf = *reinterpret_cast<const short8*>(
            kb + (kt*16 + qi)*256 + ((ks*64 + g*16) ^ (qi<<4)));
        s = __builtin_amdgcn_mfma_f32_16x16x32_bf16(kf, qf[ks], s, 0, 0, 0);
      }
      st[kt] = s;
    }
    float p[4][4];
    float cmax = NEGINF;
    if (j == nch - 1){
      #pragma unroll
      for (int kt=0; kt<4; ++kt)
        #pragma unroll
        for (int r=0; r<4; ++r){
          int key = k0 + kt*16 + 4*g + r;
          float v = st[kt][r]*0.1f; if (key > qglob) v = NEGINF;
          p[kt][r] = v; cmax = fmaxf(cmax, v);
        }
    } else {
      #pragma unroll
      for (int kt=0; kt<4; ++kt)
        #pragma unroll
        for (int r=0; r<4; ++r){
          float v = st[kt][r]*0.1f;
          p[kt][r] = v; cmax = fmaxf(cmax, v);
        }
    }
    cmax = fmaxf(cmax, __shfl_xor(cmax, 16));
    cmax = fmaxf(cmax, __shfl_xor(cmax, 32));
    float mnew = fmaxf(m, cmax);
    float scale = __expf(m - mnew);
    m = mnew;
    float rs = 0.f;
    #pragma unroll
    for (int kt=0; kt<4; ++kt)
      #pragma unroll
      for (int r=0; r<4; ++r){
        p[kt][r] = __expf(p[kt][r] - m);
        rs += p[kt][r];
      }
    rs += __shfl_xor(rs, 16);
    rs += __shfl_xor(rs, 32);
    lr = lr*scale + rs;
    float scr[4];
    #pragma unroll
    for (int r=0; r<4; ++r) scr[r] = __shfl(scale, 20*g + r);
    #pragma unroll
    for (int dt=0; dt<7; ++dt){
      acc[dt][0]*=scr[0]; acc[dt][1]*=scr[1]; acc[dt][2]*=scr[2]; acc[dt][3]*=scr[3];
    }
    #pragma unroll
    for (int kt=0; kt<4; ++kt){
      pbase[kt*8 + 2*g    ] = pk2(p[kt][0], p[kt][1]);
      pbase[kt*8 + 2*g + 1] = pk2(p[kt][2], p[kt][3]);
    }
    #pragma unroll
    for (int ks=0; ks<2; ++ks){
      short8 pa = *reinterpret_cast<const short8*>(pbase + 16*ks + 4*g);
      const bf16* vp = Vbase + k0 + ks*32 + g*8;
      #pragma unroll
      for (int dt=0; dt<7; ++dt){
        short8 vf = *reinterpret_cast<const short8*>(vp + (size_t)(dt*16 + qi)*T_);
        acc[dt] = __builtin_amdgcn_mfma_f32_16x16x32_bf16(pa, vf, acc[dt], 0, 0, 0);
      }
    }
    __syncthreads();
  }
  float inv = 1.f / lr;
  float invr[4];
  #pragma unroll
  for (int r=0; r<4; ++r) invr[r] = __shfl(inv, 20*g + r);
  int b = bh >> 2, h = bh & 3;
  #pragma unroll
  for (int dt=0; dt<7; ++dt){
    int d = dt*16 + qi;
    if (d < D_){
      #pragma unroll
      for (int r=0; r<4; ++r){
        size_t row = (size_t)(b*T_) + q0 + 4*g + r;
        AOb[row*KP + h*D_ + d] = f2bf(acc[dt][r] * invr[r]);
      }
    }
  }
  #undef STAGE
}

// ---------------------------------------------------------------------------
extern "C" void kernel_launch(void* const* d_in, const int* in_sizes, int n_in,
                              void* d_out, int out_size, void* d_ws, size_t ws_size,
                              hipStream_t stream){
  const float* x  = (const float*)d_in[0];
  const float* Wq = (const float*)d_in[1];
  const float* Wk = (const float*)d_in[2];
  const float* Wv = (const float*)d_in[3];
  const float* Wo = (const float*)d_in[4];
  const float* bo = (const float*)d_in[5];

  constexpr size_t NBH  = (size_t)B_*H_;                 // 32
  constexpr size_t NPAD = NBH*T_*DP;                     // 8,388,608 elems
  constexpr size_t NROW = (size_t)B_*T_;                 // 16384
  constexpr size_t OFF_QP  = 0;
  constexpr size_t OFF_KP  = OFF_QP + NPAD*2;
  constexpr size_t OFF_VT  = OFF_KP + NPAD*2;
  constexpr size_t OFF_XB  = OFF_VT + NPAD*2;
  constexpr size_t OFF_AOB = OFF_XB + NROW*KP*2;
  constexpr size_t OFF_WT  = OFF_AOB + NROW*KP*2;
  constexpr size_t OFF_WOB = OFF_WT + (size_t)12*128*KP*2;
  constexpr size_t TOTAL   = OFF_WOB + (size_t)512*KP*2; // ~79.3 MB
  if (ws_size < TOTAL) return;   // visible failure signature (output stays zero)

  char* ws = (char*)d_ws;
  bf16*  Qp   = (bf16*)(ws + OFF_QP);
  bf16*  Kp   = (bf16*)(ws + OFF_KP);
  bf16*  VTp  = (bf16*)(ws + OFF_VT);
  bf16*  xb   = (bf16*)(ws + OFF_XB);
  bf16*  AOb  = (bf16*)(ws + OFF_AOB);
  bf16*  WT   = (bf16*)(ws + OFF_WT);
  bf16*  WoB  = (bf16*)(ws + OFF_WOB);
  float* out  = (float*)d_out;

  conv_x_kernel<<<(16384*52 + 255)/256, 256, 0, stream>>>(x, xb);
  prep_wqkv_kernel<<<(12*128*KP + 255)/256, 256, 0, stream>>>(Wq, Wk, Wv, WT);
  prep_wo_kernel<<<(512*KP + 255)/256, 256, 0, stream>>>(Wo, WoB);
  zero_aopad_kernel<<<128, 256, 0, stream>>>(AOb);
  qkv_gemm_kernel<<<1536, 256, 0, stream>>>(xb, WT, Qp, Kp, VTp);
  attn_kernel<<<NBH*32, 256, 0, stream>>>(Qp, Kp, VTp, AOb);
  out_gemm_kernel<<<512, 256, 0, stream>>>(AOb, WoB, bo, out);
}

// Round 8
// 166.380 us; speedup vs baseline: 38.2590x; 1.5632x over previous
//
#include <hip/hip_runtime.h>
#include <hip/hip_bf16.h>

#define B_ 8
#define T_ 2048
#define C_ 400
#define H_ 4
#define D_ 100
#define DP 128
#define KP 416   // C_ padded to 13*32
#define KPB 832  // KP bytes (bf16)

typedef __hip_bfloat16 bf16;
typedef unsigned int uint32;
typedef __attribute__((ext_vector_type(8))) short short8;
typedef __attribute__((ext_vector_type(4))) float f32x4;

__device__ __forceinline__ float bf2f(bf16 v){ return __bfloat162float(v); }
__device__ __forceinline__ bf16 f2bf(float f){ return __float2bfloat16(f); }
__device__ __forceinline__ unsigned short bfbits(float f){
  bf16 h = f2bf(f);
  return __builtin_bit_cast(unsigned short, h);
}
__device__ __forceinline__ uint32 pk2(float a, float b){
  return (uint32)bfbits(a) | ((uint32)bfbits(b) << 16);
}
__device__ __forceinline__ void gl_lds16(const char* gsrc, char* ldst){
  __builtin_amdgcn_global_load_lds(
      (const __attribute__((address_space(1))) unsigned int*)gsrc,
      (__attribute__((address_space(3))) unsigned int*)ldst, 16, 0, 0);
}

// ---------------------------------------------------------------------------
// x fp32 [16384][400] -> xb bf16 [16384][416], pad cols zero. uint4 writes.
__global__ __launch_bounds__(256) void conv_x_kernel(const float* __restrict__ x,
    bf16* __restrict__ xb){
  int i = blockIdx.x*256 + threadIdx.x;          // over 16384*52
  if (i >= 16384*52) return;
  int c8 = i % 52, t = i / 52;
  uint32 u[4];
  if (c8 < 50){
    const float* src = x + (size_t)t*C_ + c8*8;
    #pragma unroll
    for (int k=0;k<4;++k) u[k] = pk2(src[2*k], src[2*k+1]);
  } else {
    u[0]=u[1]=u[2]=u[3]=0;
  }
  *reinterpret_cast<uint4*>((char*)xb + (size_t)t*KPB + c8*16) = make_uint4(u[0],u[1],u[2],u[3]);
}

// Wq/Wk/Wv [H][C][D] fp32 -> WT [12][128][416] bf16: WT[p*4+h][d][c] = W_p[h][c][d],
// zero-padded (d>=100 or c>=400). Dest-coalesced; strided source absorbed by L2.
__global__ __launch_bounds__(256) void prep_wqkv_kernel(const float* __restrict__ Wq,
    const float* __restrict__ Wk, const float* __restrict__ Wv, bf16* __restrict__ WT){
  int i = blockIdx.x*256 + threadIdx.x;          // over 12*128*416
  if (i >= 12*128*KP) return;
  int c = i % KP, n = (i/KP) & 127, group = i/(KP*128);
  int p = group >> 2, h = group & 3;
  float v = 0.f;
  if (n < D_ && c < C_){
    const float* W = (p==0)?Wq:(p==1)?Wk:Wv;
    v = W[((size_t)h*C_ + c)*D_ + n];
  }
  WT[i] = f2bf(v);
}

// Wo [400][400] fp32 -> WoB [512][416] bf16 zero-padded (rows of W^T layout).
__global__ __launch_bounds__(256) void prep_wo_kernel(const float* __restrict__ Wo,
    bf16* __restrict__ WoB){
  int i = blockIdx.x*256 + threadIdx.x;          // over 512*416
  if (i >= 512*KP) return;
  int c = i % KP, n = i / KP;
  float v = (n < C_ && c < C_) ? Wo[(size_t)n*C_ + c] : 0.f;
  WoB[i] = f2bf(v);
}

// AOb pad cols 400..415 = 0 (once per call; attn writes only cols<400).
__global__ __launch_bounds__(256) void zero_aopad_kernel(bf16* __restrict__ AOb){
  int i = blockIdx.x*256 + threadIdx.x;          // over 16384*2
  if (i >= 16384*2) return;
  int row = i >> 1, half = i & 1;
  *reinterpret_cast<uint4*>((char*)AOb + (size_t)row*KPB + 800 + half*16) = make_uint4(0,0,0,0);
}

// ---------------------------------------------------------------------------
// QKV MFMA GEMM (unchanged from R7): C = xb * WT_g^T per (p,h) group.
__global__ __launch_bounds__(256) void qkv_gemm_kernel(const bf16* __restrict__ xb,
    const bf16* __restrict__ WT, bf16* __restrict__ Qp, bf16* __restrict__ Kp,
    bf16* __restrict__ VT){
  __shared__ __align__(16) char xs[2][8192];
  __shared__ __align__(16) char wsh[2][8192];
  int bid = blockIdx.x;
  int xcd = bid & 7, idx = bid >> 3;             // idx 0..191
  int mb = xcd*16 + idx/12;
  int group = idx % 12;
  int p = group >> 2, h = group & 3;
  int t0 = mb * 128;
  int tid = threadIdx.x;
  int w = tid >> 6, l = tid & 63, g = l >> 4, qi = l & 15;
  const char* xg = (const char*)xb + (size_t)t0*KPB;
  const char* wg = (const char*)WT + (size_t)group*128*KPB;
  int srow = tid >> 2, sseg = tid & 3;

  #define GSTAGE(J, BUF) {                                                     \
    int kc2 = (J)*64;                                                          \
    _Pragma("unroll")                                                          \
    for (int r2=0;r2<2;++r2)                                                   \
      gl_lds16(xg + (size_t)(srow + r2*64)*KPB + kc2 + sseg*16,                \
               &xs[BUF][tid*16 + r2*4096]);                                    \
    _Pragma("unroll")                                                          \
    for (int r2=0;r2<2;++r2)                                                   \
      gl_lds16(wg + (size_t)(srow + r2*64)*KPB + kc2 + sseg*16,                \
               &wsh[BUF][tid*16 + r2*4096]); }

  f32x4 acc[2][8];
  #pragma unroll
  for (int mt=0;mt<2;++mt)
    #pragma unroll
    for (int nt=0;nt<8;++nt) acc[mt][nt] = (f32x4){0.f,0.f,0.f,0.f};

  GSTAGE(0, 0)
  __syncthreads();
  for (int j = 0; j < 13; ++j){
    int cur = j & 1;
    if (j < 12) GSTAGE(j+1, cur^1)
    short8 af[2];
    #pragma unroll
    for (int mt=0;mt<2;++mt)
      af[mt] = *reinterpret_cast<const short8*>(&xs[cur][(w*32 + mt*16 + qi)*64 + g*16]);
    short8 bfr[8];
    #pragma unroll
    for (int nt=0;nt<8;++nt)
      bfr[nt] = *reinterpret_cast<const short8*>(&wsh[cur][(nt*16 + qi)*64 + g*16]);
    if (p < 2){
      #pragma unroll
      for (int mt=0;mt<2;++mt)
        #pragma unroll
        for (int nt=0;nt<8;++nt)
          acc[mt][nt] = __builtin_amdgcn_mfma_f32_16x16x32_bf16(af[mt], bfr[nt], acc[mt][nt], 0,0,0);
    } else {
      #pragma unroll
      for (int mt=0;mt<2;++mt)
        #pragma unroll
        for (int nt=0;nt<8;++nt)
          acc[mt][nt] = __builtin_amdgcn_mfma_f32_16x16x32_bf16(bfr[nt], af[mt], acc[mt][nt], 0,0,0);
    }
    __syncthreads();
  }

  int b = t0 >> 11, tloc0 = t0 & 2047;
  size_t bh = (size_t)b*H_ + h;
  if (p < 2){
    bf16* dst = (p==0 ? Qp : Kp) + (bh*T_ + tloc0)*DP;
    #pragma unroll
    for (int mt=0;mt<2;++mt)
      #pragma unroll
      for (int r=0;r<4;++r){
        int tr = w*32 + mt*16 + 4*g + r;
        #pragma unroll
        for (int nt=0;nt<8;++nt)
          dst[(size_t)tr*DP + nt*16 + qi] = f2bf(acc[mt][nt][r]);
      }
  } else {
    bf16* dstv = VT + bh*DP*T_ + tloc0;
    #pragma unroll
    for (int nt=0;nt<8;++nt)
      #pragma unroll
      for (int r=0;r<4;++r){
        int d = nt*16 + 4*g + r;
        #pragma unroll
        for (int mt=0;mt<2;++mt)
          dstv[(size_t)d*T_ + w*32 + mt*16 + qi] = f2bf(acc[mt][nt][r]);
      }
  }
  #undef GSTAGE
}

// ---------------------------------------------------------------------------
// Out-proj MFMA GEMM (unchanged from R7).
__global__ __launch_bounds__(256) void out_gemm_kernel(const bf16* __restrict__ AOb,
    const bf16* __restrict__ WoB, const float* __restrict__ bo, float* __restrict__ out){
  __shared__ __align__(16) char xs[2][8192];
  __shared__ __align__(16) char wsh[2][8192];
  int bid = blockIdx.x;
  int xcd = bid & 7, idx = bid >> 3;             // idx 0..63
  int mb = xcd*16 + idx/4;
  int nb = idx & 3;
  int t0 = mb * 128, n0 = nb * 128;
  int tid = threadIdx.x;
  int w = tid >> 6, l = tid & 63, g = l >> 4, qi = l & 15;
  const char* xg = (const char*)AOb + (size_t)t0*KPB;
  const char* wg = (const char*)WoB + (size_t)n0*KPB;
  int srow = tid >> 2, sseg = tid & 3;

  #define GSTAGE(J, BUF) {                                                     \
    int kc2 = (J)*64;                                                          \
    _Pragma("unroll")                                                          \
    for (int r2=0;r2<2;++r2)                                                   \
      gl_lds16(xg + (size_t)(srow + r2*64)*KPB + kc2 + sseg*16,                \
               &xs[BUF][tid*16 + r2*4096]);                                    \
    _Pragma("unroll")                                                          \
    for (int r2=0;r2<2;++r2)                                                   \
      gl_lds16(wg + (size_t)(srow + r2*64)*KPB + kc2 + sseg*16,                \
               &wsh[BUF][tid*16 + r2*4096]); }

  f32x4 acc[2][8];
  #pragma unroll
  for (int mt=0;mt<2;++mt)
    #pragma unroll
    for (int nt=0;nt<8;++nt) acc[mt][nt] = (f32x4){0.f,0.f,0.f,0.f};

  GSTAGE(0, 0)
  __syncthreads();
  for (int j = 0; j < 13; ++j){
    int cur = j & 1;
    if (j < 12) GSTAGE(j+1, cur^1)
    short8 af[2];
    #pragma unroll
    for (int mt=0;mt<2;++mt)
      af[mt] = *reinterpret_cast<const short8*>(&xs[cur][(w*32 + mt*16 + qi)*64 + g*16]);
    short8 bfr[8];
    #pragma unroll
    for (int nt=0;nt<8;++nt)
      bfr[nt] = *reinterpret_cast<const short8*>(&wsh[cur][(nt*16 + qi)*64 + g*16]);
    #pragma unroll
    for (int mt=0;mt<2;++mt)
      #pragma unroll
      for (int nt=0;nt<8;++nt)
        acc[mt][nt] = __builtin_amdgcn_mfma_f32_16x16x32_bf16(af[mt], bfr[nt], acc[mt][nt], 0,0,0);
    __syncthreads();
  }

  #pragma unroll
  for (int nt=0;nt<8;++nt){
    if (n0 + nt*16 >= C_) continue;              // wave-uniform (400 % 16 == 0)
    int n = n0 + nt*16 + qi;
    float bv = bo[n];
    #pragma unroll
    for (int mt=0;mt<2;++mt)
      #pragma unroll
      for (int r=0;r<4;++r){
        int tr = w*32 + mt*16 + 4*g + r;
        out[(size_t)(t0 + tr)*C_ + n] = acc[mt][nt][r] + bv;
      }
  }
  #undef GSTAGE
}

// ---------------------------------------------------------------------------
// MFMA flash attention v4: K-tile AND V-slab both LDS-staged double-buffered
// via global_load_lds(16B), pre-swizzled sources (T21). V slab [112][64] bf16
// (rows 128B, XOR (row&7)<<4 -> PV read slot = g^(qi&7): conflict-free).
// Removes the R7 pathology: 14 uncoalesced global V b128 loads per chunk
// serialized through a 72-VGPR budget; V latency now hidden behind barrier
// and shared by all 4 waves. s_setprio(1) around MFMA clusters (T5).
__global__ __launch_bounds__(256) void attn_kernel(const bf16* __restrict__ Qp,
    const bf16* __restrict__ Kp, const bf16* __restrict__ VT, bf16* __restrict__ AOb){
  __shared__ __align__(16) char ktile[2][16384];
  __shared__ __align__(16) char vtile[2][14336];
  __shared__ __align__(16) uint32 pshare[4*16*36];
  const float NEGINF = -__builtin_inff();
  int bid = blockIdx.x;
  int xcd = bid & 7, idx = bid >> 3;
  int bh  = xcd*4 + (idx >> 5);
  int qb  = 31 - (idx & 31);
  int tid = threadIdx.x;
  int w = tid >> 6, l = tid & 63;
  int g = l >> 4, qi = l & 15;
  int q0 = qb*64 + w*16;

  const bf16* Qrow  = Qp + ((size_t)bh*T_ + q0 + qi)*DP + g*8;
  const char* Kg    = (const char*)(Kp + (size_t)bh*T_*DP);
  const char* Vg    = (const char*)(VT + (size_t)bh*DP*T_);   // row d: 4096B stride

  short8 qf[4];
  #pragma unroll
  for (int ks=0; ks<4; ++ks)
    qf[ks] = *reinterpret_cast<const short8*>(Qrow + ks*32);

  f32x4 acc[7];
  #pragma unroll
  for (int dt=0; dt<7; ++dt) acc[dt] = (f32x4){0.f,0.f,0.f,0.f};
  float m = NEGINF, lr = 0.f;

  uint32* pbase = &pshare[(w*16 + qi)*36];
  int qglob = q0 + qi;
  int nch = qb + 1;

  // K: wave w stages rows [w*16, w*16+16): 4 x 64 lanes x 16B = 4KB
  int st_off0 = w*4096 + l*16;
  #define STAGE(J, BUF) { int k0s = (J) << 6;                                   \
    _Pragma("unroll")                                                           \
    for (int it=0; it<4; ++it){                                                 \
      int off = st_off0 + it*1024;                                              \
      int row = off >> 8;                                                       \
      int cb  = off & 255;                                                      \
      gl_lds16(Kg + (size_t)(k0s + row)*256 + (cb ^ ((row&15)<<4)),             \
               &ktile[BUF][w*4096 + it*1024]); } }

  // V: slab rows d=0..111 (128B each), 14 issues round-robined over waves.
  // issue it: rows it*8 + (l>>3), slot l&7; src col-XOR (row&7)<<4 = (l>>3)<<4.
  #define VSTAGE(J, BUF) { int k0s2 = ((J) << 6)*2;                             \
    for (int it=w; it<14; it+=4){                                               \
      int off = it*1024 + l*16;                                                 \
      int row = off >> 7;                                                       \
      int cb  = off & 127;                                                      \
      gl_lds16(Vg + (size_t)row*(T_*2) + k0s2 + (cb ^ ((row&7)<<4)),            \
               &vtile[BUF][it*1024 + l*16]); } }

  STAGE(0, 0)
  VSTAGE(0, 0)
  __syncthreads();

  for (int j = 0; j < nch; ++j){
    int k0 = j << 6;
    int cur = j & 1;
    if (j + 1 < nch){ STAGE(j+1, cur^1) VSTAGE(j+1, cur^1) }
    const char* kb = ktile[cur];
    const char* vb = vtile[cur];
    // ---- S^T tiles: 4 key-tiles x 4 k-slabs ----
    f32x4 st[4];
    __builtin_amdgcn_s_setprio(1);
    #pragma unroll
    for (int kt=0; kt<4; ++kt){
      f32x4 s = (f32x4){0.f,0.f,0.f,0.f};
      #pragma unroll
      for (int ks=0; ks<4; ++ks){
        short8 kf = *reinterpret_cast<const short8*>(
            kb + (kt*16 + qi)*256 + ((ks*64 + g*16) ^ (qi<<4)));
        s = __builtin_amdgcn_mfma_f32_16x16x32_bf16(kf, qf[ks], s, 0, 0, 0);
      }
      st[kt] = s;
    }
    __builtin_amdgcn_s_setprio(0);
    // ---- mask (last chunk only) + online softmax ----
    float p[4][4];
    float cmax = NEGINF;
    if (j == nch - 1){
      #pragma unroll
      for (int kt=0; kt<4; ++kt)
        #pragma unroll
        for (int r=0; r<4; ++r){
          int key = k0 + kt*16 + 4*g + r;
          float v = st[kt][r]*0.1f; if (key > qglob) v = NEGINF;
          p[kt][r] = v; cmax = fmaxf(cmax, v);
        }
    } else {
      #pragma unroll
      for (int kt=0; kt<4; ++kt)
        #pragma unroll
        for (int r=0; r<4; ++r){
          float v = st[kt][r]*0.1f;
          p[kt][r] = v; cmax = fmaxf(cmax, v);
        }
    }
    cmax = fmaxf(cmax, __shfl_xor(cmax, 16));
    cmax = fmaxf(cmax, __shfl_xor(cmax, 32));
    float mnew = fmaxf(m, cmax);
    float scale = __expf(m - mnew);
    m = mnew;
    float rs = 0.f;
    #pragma unroll
    for (int kt=0; kt<4; ++kt)
      #pragma unroll
      for (int r=0; r<4; ++r){
        p[kt][r] = __expf(p[kt][r] - m);
        rs += p[kt][r];
      }
    rs += __shfl_xor(rs, 16);
    rs += __shfl_xor(rs, 32);
    lr = lr*scale + rs;
    float scr[4];
    #pragma unroll
    for (int r=0; r<4; ++r) scr[r] = __shfl(scale, 20*g + r);
    #pragma unroll
    for (int dt=0; dt<7; ++dt){
      acc[dt][0]*=scr[0]; acc[dt][1]*=scr[1]; acc[dt][2]*=scr[2]; acc[dt][3]*=scr[3];
    }
    // ---- P bounce: write [q=qi][key/2 dwords], read A-frags ----
    #pragma unroll
    for (int kt=0; kt<4; ++kt){
      pbase[kt*8 + 2*g    ] = pk2(p[kt][0], p[kt][1]);
      pbase[kt*8 + 2*g + 1] = pk2(p[kt][2], p[kt][3]);
    }
    // ---- PV from LDS V-slab: O[q][d] += P[q][key] * V[key][d] ----
    __builtin_amdgcn_s_setprio(1);
    #pragma unroll
    for (int ks=0; ks<2; ++ks){
      short8 pa = *reinterpret_cast<const short8*>(pbase + 16*ks + 4*g); // same-wave RAW
      #pragma unroll
      for (int dt=0; dt<7; ++dt){
        int row = dt*16 + qi;
        short8 vf = *reinterpret_cast<const short8*>(
            vb + row*128 + ((ks*64 + g*16) ^ ((qi&7)<<4)));
        acc[dt] = __builtin_amdgcn_mfma_f32_16x16x32_bf16(pa, vf, acc[dt], 0, 0, 0);
      }
    }
    __builtin_amdgcn_s_setprio(0);
    __syncthreads();   // drains vmcnt (next K+V staged a full chunk ago)
  }
  float inv = 1.f / lr;
  float invr[4];
  #pragma unroll
  for (int r=0; r<4; ++r) invr[r] = __shfl(inv, 20*g + r);
  int b = bh >> 2, h = bh & 3;
  #pragma unroll
  for (int dt=0; dt<7; ++dt){
    int d = dt*16 + qi;
    if (d < D_){
      #pragma unroll
      for (int r=0; r<4; ++r){
        size_t row = (size_t)(b*T_) + q0 + 4*g + r;
        AOb[row*KP + h*D_ + d] = f2bf(acc[dt][r] * invr[r]);
      }
    }
  }
  #undef STAGE
  #undef VSTAGE
}

// ---------------------------------------------------------------------------
extern "C" void kernel_launch(void* const* d_in, const int* in_sizes, int n_in,
                              void* d_out, int out_size, void* d_ws, size_t ws_size,
                              hipStream_t stream){
  const float* x  = (const float*)d_in[0];
  const float* Wq = (const float*)d_in[1];
  const float* Wk = (const float*)d_in[2];
  const float* Wv = (const float*)d_in[3];
  const float* Wo = (const float*)d_in[4];
  const float* bo = (const float*)d_in[5];

  constexpr size_t NBH  = (size_t)B_*H_;                 // 32
  constexpr size_t NPAD = NBH*T_*DP;                     // 8,388,608 elems
  constexpr size_t NROW = (size_t)B_*T_;                 // 16384
  constexpr size_t OFF_QP  = 0;
  constexpr size_t OFF_KP  = OFF_QP + NPAD*2;
  constexpr size_t OFF_VT  = OFF_KP + NPAD*2;
  constexpr size_t OFF_XB  = OFF_VT + NPAD*2;
  constexpr size_t OFF_AOB = OFF_XB + NROW*KP*2;
  constexpr size_t OFF_WT  = OFF_AOB + NROW*KP*2;
  constexpr size_t OFF_WOB = OFF_WT + (size_t)12*128*KP*2;
  constexpr size_t TOTAL   = OFF_WOB + (size_t)512*KP*2; // ~79.3 MB
  if (ws_size < TOTAL) return;   // visible failure signature (output stays zero)

  char* ws = (char*)d_ws;
  bf16*  Qp   = (bf16*)(ws + OFF_QP);
  bf16*  Kp   = (bf16*)(ws + OFF_KP);
  bf16*  VTp  = (bf16*)(ws + OFF_VT);
  bf16*  xb   = (bf16*)(ws + OFF_XB);
  bf16*  AOb  = (bf16*)(ws + OFF_AOB);
  bf16*  WT   = (bf16*)(ws + OFF_WT);
  bf16*  WoB  = (bf16*)(ws + OFF_WOB);
  float* out  = (float*)d_out;

  conv_x_kernel<<<(16384*52 + 255)/256, 256, 0, stream>>>(x, xb);
  prep_wqkv_kernel<<<(12*128*KP + 255)/256, 256, 0, stream>>>(Wq, Wk, Wv, WT);
  prep_wo_kernel<<<(512*KP + 255)/256, 256, 0, stream>>>(Wo, WoB);
  zero_aopad_kernel<<<128, 256, 0, stream>>>(AOb);
  qkv_gemm_kernel<<<1536, 256, 0, stream>>>(xb, WT, Qp, Kp, VTp);
  attn_kernel<<<NBH*32, 256, 0, stream>>>(Qp, Kp, VTp, AOb);
  out_gemm_kernel<<<512, 256, 0, stream>>>(AOb, WoB, bo, out);
}